// Round 1
// baseline (923.910 us; speedup 1.0000x reference)
//
#include <hip/hip_runtime.h>

#define N_NODES 50000
#define N_EDGES 800000
#define DIN 384
#define DH 128
#define NB 64
#define NEG 0.2f

// ---------------- edge-weight sum (for self-loop fill value) ----------------
__global__ void ewsum_kernel(const float* __restrict__ ew, float* __restrict__ out) {
    int i = blockIdx.x * blockDim.x + threadIdx.x;
    float v = (i < N_EDGES) ? ew[i] : 0.0f;
    #pragma unroll
    for (int o = 32; o; o >>= 1) v += __shfl_down(v, o, 64);
    if ((threadIdx.x & 63) == 0) atomicAdd(out, v);
}

// ---------------- CSR build: histogram, scan, fill ----------------
__global__ void hist_kernel(const int* __restrict__ dst, int* __restrict__ cnt) {
    int e = blockIdx.x * blockDim.x + threadIdx.x;
    if (e < N_EDGES) atomicAdd(&cnt[dst[e]], 1);
}

__global__ void scan_a(const int* __restrict__ cnt, int* __restrict__ scanned,
                       int* __restrict__ bsums) {
    __shared__ int s[256];
    int tid = threadIdx.x;
    int i = blockIdx.x * 256 + tid;
    int v = (i < N_NODES) ? cnt[i] : 0;
    s[tid] = v; __syncthreads();
    for (int o = 1; o < 256; o <<= 1) {
        int t = (tid >= o) ? s[tid - o] : 0;
        __syncthreads();
        s[tid] += t;
        __syncthreads();
    }
    if (i < N_NODES) scanned[i] = s[tid] - v;  // exclusive
    if (tid == 255) bsums[blockIdx.x] = s[255];
}

__global__ void scan_b(int* __restrict__ bsums, int nb) {
    __shared__ int s[256];
    int tid = threadIdx.x;
    int v = (tid < nb) ? bsums[tid] : 0;
    s[tid] = v; __syncthreads();
    for (int o = 1; o < 256; o <<= 1) {
        int t = (tid >= o) ? s[tid - o] : 0;
        __syncthreads();
        s[tid] += t;
        __syncthreads();
    }
    if (tid < nb) bsums[tid] = s[tid] - v;  // exclusive
}

__global__ void scan_c(const int* __restrict__ scanned, const int* __restrict__ bsums,
                       const int* __restrict__ cnt, int* __restrict__ ptr,
                       int* __restrict__ cursor) {
    int i = blockIdx.x * 256 + threadIdx.x;
    if (i < N_NODES) {
        int p = scanned[i] + bsums[blockIdx.x];
        ptr[i] = p;
        cursor[i] = p;
        if (i == N_NODES - 1) ptr[N_NODES] = p + cnt[i];
    }
}

__global__ void fill_kernel(const int* __restrict__ dst, int* __restrict__ cursor,
                            int* __restrict__ eids) {
    int e = blockIdx.x * blockDim.x + threadIdx.x;
    if (e < N_EDGES) {
        int p = atomicAdd(&cursor[dst[e]], 1);
        eids[p] = e;
    }
}

// ---------------- fp32 GEMM: C[M,128] = A[M,K] @ W[K,128] (+bias) ----------------
template<int K>
__global__ __launch_bounds__(256) void gemm_kernel(const float* __restrict__ A,
                                                   const float* __restrict__ W,
                                                   const float* __restrict__ bias,
                                                   float* __restrict__ C, int M)
{
    __shared__ float As[8][64];     // [k][m]
    __shared__ float Ws[8][DH];     // [k][n]
    const int tid = threadIdx.x;
    const int tx = tid & 31;        // 32 threads across N, 4 cols each
    const int ty = tid >> 5;        // 8 thread-rows, 8 rows each
    const int m0 = blockIdx.x * 64;
    const int lr = tid >> 2;        // load: row within A tile
    const int lk = (tid & 3) * 2;   // load: k pair
    const int wk = tid >> 5;        // load: W tile k
    const int wc = (tid & 31) * 4;  // load: W tile col
    float acc[8][4] = {};
    int arow = m0 + lr; if (arow >= M) arow = M - 1;
    const float* Aptr = A + (size_t)arow * K + lk;

    for (int k0 = 0; k0 < K; k0 += 8) {
        float2 av = *(const float2*)(Aptr + k0);
        float4 wv = *(const float4*)(W + (size_t)(k0 + wk) * DH + wc);
        As[lk][lr] = av.x; As[lk + 1][lr] = av.y;
        *(float4*)&Ws[wk][wc] = wv;
        __syncthreads();
        #pragma unroll
        for (int k = 0; k < 8; ++k) {
            float a[8];
            *(float4*)&a[0] = *(const float4*)&As[k][ty * 8];
            *(float4*)&a[4] = *(const float4*)&As[k][ty * 8 + 4];
            float4 wf = *(const float4*)&Ws[k][tx * 4];
            #pragma unroll
            for (int r = 0; r < 8; ++r) {
                acc[r][0] = fmaf(a[r], wf.x, acc[r][0]);
                acc[r][1] = fmaf(a[r], wf.y, acc[r][1]);
                acc[r][2] = fmaf(a[r], wf.z, acc[r][2]);
                acc[r][3] = fmaf(a[r], wf.w, acc[r][3]);
            }
        }
        __syncthreads();
    }
    float4 bv = {0.f, 0.f, 0.f, 0.f};
    if (bias) bv = *(const float4*)(bias + tx * 4);
    #pragma unroll
    for (int r = 0; r < 8; ++r) {
        int row = m0 + ty * 8 + r;
        if (row < M) {
            float4 o;
            o.x = acc[r][0] + bv.x; o.y = acc[r][1] + bv.y;
            o.z = acc[r][2] + bv.z; o.w = acc[r][3] + bv.w;
            *(float4*)(C + (size_t)row * DH + tx * 4) = o;
        }
    }
}

// ---------------- per-node attention logits a_src, a_dst ----------------
__global__ __launch_bounds__(128) void att_kernel(const float* __restrict__ h,
        const float* __restrict__ a_s, const float* __restrict__ a_d,
        float* __restrict__ asrc, float* __restrict__ adst)
{
    int n = blockIdx.x, t = threadIdx.x;
    float v = h[(size_t)n * DH + t];
    float ps = v * a_s[t], pd = v * a_d[t];
    #pragma unroll
    for (int o = 16; o; o >>= 1) { ps += __shfl_down(ps, o, 32); pd += __shfl_down(pd, o, 32); }
    if ((t & 31) == 0) { int hd = t >> 5; asrc[(size_t)n * 4 + hd] = ps; adst[(size_t)n * 4 + hd] = pd; }
}

// ---------------- per-dst aggregation + softmax + bias + LN + ELU + residual ----------------
__global__ __launch_bounds__(128) void msg_kernel(
    const float* __restrict__ h, const float* __restrict__ asrc,
    const float* __restrict__ adst, const float* __restrict__ xres,
    const int* __restrict__ indptr, const int* __restrict__ eids,
    const int* __restrict__ srcarr, const float* __restrict__ ew,
    const float* __restrict__ ewsum,
    const float* __restrict__ Wedge, const float* __restrict__ aedge,
    const float* __restrict__ bias, const float* __restrict__ gamma,
    const float* __restrict__ beta, float* __restrict__ xout)
{
    const int n = blockIdx.x, t = threadIdx.x, hd = t >> 5;
    __shared__ float cL[4], adL[4], scL[4], dL[4];
    __shared__ int srcL[128];
    __shared__ float alL[128][4];
    __shared__ float r1[2], r2[2];

    // c[h] = dot(We_h, ae_h): a_eg[e,h] = ew[e]*c[h]
    float prod = Wedge[t] * aedge[t];
    #pragma unroll
    for (int o = 16; o; o >>= 1) prod += __shfl_down(prod, o, 32);
    if ((t & 31) == 0) cL[hd] = prod;
    if (t < 4) adL[t] = adst[(size_t)n * 4 + t];
    __syncthreads();

    const float ewm = ewsum[0] * (1.0f / N_EDGES);
    // self-loop folded into online-softmax initial state
    float mreg = 0.f, dreg = 0.f;
    if (t < 4) {
        float a0 = asrc[(size_t)n * 4 + t] + adL[t] + ewm * cL[t];
        a0 = a0 > 0.f ? a0 : NEG * a0;
        mreg = a0; dreg = 1.0f;
    }
    float acc = h[(size_t)n * DH + t];   // exp(alpha_self - m) = 1 at init

    const int st = indptr[n], en = indptr[n + 1];
    for (int base = st; base < en; base += 128) {
        const int cb = min(128, en - base);
        __syncthreads();   // protect LDS reuse across chunks
        if (t < cb) {
            const int eid = eids[base + t];
            const int s = srcarr[eid];
            const float wgt = ew[eid];
            srcL[t] = s;
            const float4 a4 = *(const float4*)(asrc + (size_t)s * 4);
            float v0 = a4.x + adL[0] + wgt * cL[0];
            float v1 = a4.y + adL[1] + wgt * cL[1];
            float v2 = a4.z + adL[2] + wgt * cL[2];
            float v3 = a4.w + adL[3] + wgt * cL[3];
            alL[t][0] = v0 > 0.f ? v0 : NEG * v0;
            alL[t][1] = v1 > 0.f ? v1 : NEG * v1;
            alL[t][2] = v2 > 0.f ? v2 : NEG * v2;
            alL[t][3] = v3 > 0.f ? v3 : NEG * v3;
        }
        __syncthreads();
        if (t < 4) {   // sequential online-softmax bookkeeping, one thread per head
            float chm = mreg;
            for (int j = 0; j < cb; ++j) chm = fmaxf(chm, alL[j][t]);
            const float sc = __expf(mreg - chm);
            float ds = dreg * sc;
            for (int j = 0; j < cb; ++j) {
                const float p = __expf(alL[j][t] - chm);
                alL[j][t] = p;
                ds += p;
            }
            mreg = chm; dreg = ds;
            scL[t] = sc;
        }
        __syncthreads();
        float a = acc * scL[hd];
        for (int j = 0; j < cb; ++j)
            a = fmaf(alL[j][hd], h[(size_t)srcL[j] * DH + t], a);
        acc = a;
    }
    if (t < 4) dL[t] = dreg;
    __syncthreads();

    float y = acc / (dL[hd] + 1e-16f) + bias[t];

    // LayerNorm over 128 channels + ELU + residual
    float s1 = y, s2 = y * y;
    #pragma unroll
    for (int o = 32; o; o >>= 1) { s1 += __shfl_down(s1, o, 64); s2 += __shfl_down(s2, o, 64); }
    if ((t & 63) == 0) { r1[t >> 6] = s1; r2[t >> 6] = s2; }
    __syncthreads();
    const float mu = (r1[0] + r1[1]) * (1.0f / DH);
    const float var = (r2[0] + r2[1]) * (1.0f / DH) - mu * mu;
    const float rs = rsqrtf(var + 1e-5f);
    float z = (y - mu) * rs * gamma[t] + beta[t];
    z = z > 0.f ? z : __expf(z) - 1.0f;
    xout[(size_t)n * DH + t] = z + xres[(size_t)n * DH + t];
}

// ---------------- global mean pool ----------------
#define PNODES 512
__global__ __launch_bounds__(128) void pool_kernel(const float* __restrict__ x,
        const int* __restrict__ batch, float* __restrict__ pool, int* __restrict__ gcnt)
{
    int t = threadIdx.x;
    int n0 = blockIdx.x * PNODES;
    int n1 = min(n0 + PNODES, N_NODES);
    float acc = 0.f; int cn = 0;
    int curb = batch[n0];
    for (int n = n0; n < n1; ++n) {
        int b = batch[n];
        if (b != curb) {
            atomicAdd(&pool[(size_t)curb * DH + t], acc);
            if (t == 0) atomicAdd(&gcnt[curb], cn);
            acc = 0.f; cn = 0; curb = b;
        }
        acc += x[(size_t)n * DH + t];
        ++cn;
    }
    atomicAdd(&pool[(size_t)curb * DH + t], acc);
    if (t == 0) atomicAdd(&gcnt[curb], cn);
}

__global__ void div_kernel(const float* __restrict__ pool, const int* __restrict__ gcnt,
                           float* __restrict__ out)
{
    int i = blockIdx.x * blockDim.x + threadIdx.x;
    if (i < NB * DH) {
        float c = (float)gcnt[i >> 7];
        out[i] = pool[i] / fmaxf(c, 1.0f);
    }
}

// ---------------- launch ----------------
extern "C" void kernel_launch(void* const* d_in, const int* in_sizes, int n_in,
                              void* d_out, int out_size, void* d_ws, size_t ws_size,
                              hipStream_t stream)
{
    const float* nf    = (const float*)d_in[0];
    const int*   esrc  = (const int*)d_in[1];
    const int*   edst  = esrc + N_EDGES;
    const float* ew    = (const float*)d_in[2];
    const int*   batch = (const int*)d_in[3];
    const float* Wp    = (const float*)d_in[4];
    const float* bp    = (const float*)d_in[5];
    const float* Wl[2]  = {(const float*)d_in[6],  (const float*)d_in[14]};
    const float* asl[2] = {(const float*)d_in[7],  (const float*)d_in[15]};
    const float* adl[2] = {(const float*)d_in[8],  (const float*)d_in[16]};
    const float* Wel[2] = {(const float*)d_in[9],  (const float*)d_in[17]};
    const float* ael[2] = {(const float*)d_in[10], (const float*)d_in[18]};
    const float* bl[2]  = {(const float*)d_in[11], (const float*)d_in[19]};
    const float* gl[2]  = {(const float*)d_in[12], (const float*)d_in[20]};
    const float* bel[2] = {(const float*)d_in[13], (const float*)d_in[21]};
    float* outp = (float*)d_out;

    char* w = (char*)d_ws;
    auto alloc = [&](size_t bytes) { char* p = w; w += (bytes + 255) & ~255ull; return p; };
    float* xA     = (float*)alloc((size_t)N_NODES * DH * 4);
    float* xB     = (float*)alloc((size_t)N_NODES * DH * 4);
    float* hbuf   = (float*)alloc((size_t)N_NODES * DH * 4);
    float* asrc   = (float*)alloc((size_t)N_NODES * 4 * 4);
    float* adst   = (float*)alloc((size_t)N_NODES * 4 * 4);
    float* pool   = (float*)alloc((size_t)NB * DH * 4);
    float* ews    = (float*)alloc(256);
    int* cnt      = (int*)alloc((size_t)N_NODES * 4);
    int* scanned  = (int*)alloc((size_t)N_NODES * 4);
    int* bsums    = (int*)alloc(1024);
    int* ptr      = (int*)alloc((size_t)(N_NODES + 8) * 4);
    int* cursor   = (int*)alloc((size_t)N_NODES * 4);
    int* gcnt     = (int*)alloc(256);
    int* eids     = (int*)alloc((size_t)N_EDGES * 4);

    hipMemsetAsync(ews, 0, 4, stream);
    hipMemsetAsync(cnt, 0, (size_t)N_NODES * 4, stream);
    hipMemsetAsync(pool, 0, (size_t)NB * DH * 4, stream);
    hipMemsetAsync(gcnt, 0, 256, stream);

    const int eb = (N_EDGES + 255) / 256;
    const int sb = (N_NODES + 255) / 256;  // 196

    ewsum_kernel<<<eb, 256, 0, stream>>>(ew, ews);
    hist_kernel<<<eb, 256, 0, stream>>>(edst, cnt);
    scan_a<<<sb, 256, 0, stream>>>(cnt, scanned, bsums);
    scan_b<<<1, 256, 0, stream>>>(bsums, sb);
    scan_c<<<sb, 256, 0, stream>>>(scanned, bsums, cnt, ptr, cursor);
    fill_kernel<<<eb, 256, 0, stream>>>(edst, cursor, eids);

    gemm_kernel<DIN><<<(N_NODES + 63) / 64, 256, 0, stream>>>(nf, Wp, bp, xA, N_NODES);

    const float* xin = xA;
    float* xout = xB;
    for (int l = 0; l < 2; ++l) {
        gemm_kernel<DH><<<(N_NODES + 63) / 64, 256, 0, stream>>>(xin, Wl[l], nullptr, hbuf, N_NODES);
        att_kernel<<<N_NODES, 128, 0, stream>>>(hbuf, asl[l], adl[l], asrc, adst);
        msg_kernel<<<N_NODES, 128, 0, stream>>>(hbuf, asrc, adst, xin, ptr, eids, esrc, ew, ews,
                                                Wel[l], ael[l], bl[l], gl[l], bel[l], xout);
        float* tmp = (float*)xin; xin = xout; xout = tmp;
    }

    pool_kernel<<<(N_NODES + PNODES - 1) / PNODES, 128, 0, stream>>>(xin, batch, pool, gcnt);
    div_kernel<<<(NB * DH + 255) / 256, 256, 0, stream>>>(pool, gcnt, outp);
}

// Round 2
// 764.098 us; speedup vs baseline: 1.2092x; 1.2092x over previous
//
#include <hip/hip_runtime.h>

#define N_NODES 50000
#define N_EDGES 800000
#define DIN 384
#define DH 128
#define NB 64
#define NEG 0.2f

// ---------------- edge-weight sum (for self-loop fill value) ----------------
// Grid-stride + per-block reduction: one atomic per block (was: one per wave
// with 1 elem/thread = 12500 serialized atomics = 160 us).
__global__ __launch_bounds__(256) void ewsum_kernel(const float* __restrict__ ew,
                                                    float* __restrict__ out) {
    __shared__ float sred[4];
    const int tid = threadIdx.x;
    float v = 0.0f;
    for (int i = blockIdx.x * 256 + tid; i < N_EDGES; i += gridDim.x * 256)
        v += ew[i];
    #pragma unroll
    for (int o = 32; o; o >>= 1) v += __shfl_down(v, o, 64);
    if ((tid & 63) == 0) sred[tid >> 6] = v;
    __syncthreads();
    if (tid == 0) atomicAdd(out, sred[0] + sred[1] + sred[2] + sred[3]);
}

// ---------------- CSR build: histogram, scan, fill ----------------
__global__ void hist_kernel(const int* __restrict__ dst, int* __restrict__ cnt) {
    int e = blockIdx.x * blockDim.x + threadIdx.x;
    if (e < N_EDGES) atomicAdd(&cnt[dst[e]], 1);
}

__global__ void scan_a(const int* __restrict__ cnt, int* __restrict__ scanned,
                       int* __restrict__ bsums) {
    __shared__ int s[256];
    int tid = threadIdx.x;
    int i = blockIdx.x * 256 + tid;
    int v = (i < N_NODES) ? cnt[i] : 0;
    s[tid] = v; __syncthreads();
    for (int o = 1; o < 256; o <<= 1) {
        int t = (tid >= o) ? s[tid - o] : 0;
        __syncthreads();
        s[tid] += t;
        __syncthreads();
    }
    if (i < N_NODES) scanned[i] = s[tid] - v;  // exclusive
    if (tid == 255) bsums[blockIdx.x] = s[255];
}

__global__ void scan_b(int* __restrict__ bsums, int nb) {
    __shared__ int s[256];
    int tid = threadIdx.x;
    int v = (tid < nb) ? bsums[tid] : 0;
    s[tid] = v; __syncthreads();
    for (int o = 1; o < 256; o <<= 1) {
        int t = (tid >= o) ? s[tid - o] : 0;
        __syncthreads();
        s[tid] += t;
        __syncthreads();
    }
    if (tid < nb) bsums[tid] = s[tid] - v;  // exclusive
}

__global__ void scan_c(const int* __restrict__ scanned, const int* __restrict__ bsums,
                       const int* __restrict__ cnt, int* __restrict__ ptr,
                       int* __restrict__ cursor) {
    int i = blockIdx.x * 256 + threadIdx.x;
    if (i < N_NODES) {
        int p = scanned[i] + bsums[blockIdx.x];
        ptr[i] = p;
        cursor[i] = p;
        if (i == N_NODES - 1) ptr[N_NODES] = p + cnt[i];
    }
}

__global__ void fill_kernel(const int* __restrict__ dst, int* __restrict__ cursor,
                            int* __restrict__ eids) {
    int e = blockIdx.x * blockDim.x + threadIdx.x;
    if (e < N_EDGES) {
        int p = atomicAdd(&cursor[dst[e]], 1);
        eids[p] = e;
    }
}

// ---------------- fp32 GEMM: C[M,128] = A[M,K] @ W[K,128] (+bias) ----------------
template<int K>
__global__ __launch_bounds__(256) void gemm_kernel(const float* __restrict__ A,
                                                   const float* __restrict__ W,
                                                   const float* __restrict__ bias,
                                                   float* __restrict__ C, int M)
{
    __shared__ float As[8][64];     // [k][m]
    __shared__ float Ws[8][DH];     // [k][n]
    const int tid = threadIdx.x;
    const int tx = tid & 31;        // 32 threads across N, 4 cols each
    const int ty = tid >> 5;        // 8 thread-rows, 8 rows each
    const int m0 = blockIdx.x * 64;
    const int lr = tid >> 2;        // load: row within A tile
    const int lk = (tid & 3) * 2;   // load: k pair
    const int wk = tid >> 5;        // load: W tile k
    const int wc = (tid & 31) * 4;  // load: W tile col
    float acc[8][4] = {};
    int arow = m0 + lr; if (arow >= M) arow = M - 1;
    const float* Aptr = A + (size_t)arow * K + lk;

    for (int k0 = 0; k0 < K; k0 += 8) {
        float2 av = *(const float2*)(Aptr + k0);
        float4 wv = *(const float4*)(W + (size_t)(k0 + wk) * DH + wc);
        As[lk][lr] = av.x; As[lk + 1][lr] = av.y;
        *(float4*)&Ws[wk][wc] = wv;
        __syncthreads();
        #pragma unroll
        for (int k = 0; k < 8; ++k) {
            float a[8];
            *(float4*)&a[0] = *(const float4*)&As[k][ty * 8];
            *(float4*)&a[4] = *(const float4*)&As[k][ty * 8 + 4];
            float4 wf = *(const float4*)&Ws[k][tx * 4];
            #pragma unroll
            for (int r = 0; r < 8; ++r) {
                acc[r][0] = fmaf(a[r], wf.x, acc[r][0]);
                acc[r][1] = fmaf(a[r], wf.y, acc[r][1]);
                acc[r][2] = fmaf(a[r], wf.z, acc[r][2]);
                acc[r][3] = fmaf(a[r], wf.w, acc[r][3]);
            }
        }
        __syncthreads();
    }
    float4 bv = {0.f, 0.f, 0.f, 0.f};
    if (bias) bv = *(const float4*)(bias + tx * 4);
    #pragma unroll
    for (int r = 0; r < 8; ++r) {
        int row = m0 + ty * 8 + r;
        if (row < M) {
            float4 o;
            o.x = acc[r][0] + bv.x; o.y = acc[r][1] + bv.y;
            o.z = acc[r][2] + bv.z; o.w = acc[r][3] + bv.w;
            *(float4*)(C + (size_t)row * DH + tx * 4) = o;
        }
    }
}

// ---------------- per-node attention logits a_src, a_dst ----------------
__global__ __launch_bounds__(128) void att_kernel(const float* __restrict__ h,
        const float* __restrict__ a_s, const float* __restrict__ a_d,
        float* __restrict__ asrc, float* __restrict__ adst)
{
    int n = blockIdx.x, t = threadIdx.x;
    float v = h[(size_t)n * DH + t];
    float ps = v * a_s[t], pd = v * a_d[t];
    #pragma unroll
    for (int o = 16; o; o >>= 1) { ps += __shfl_down(ps, o, 32); pd += __shfl_down(pd, o, 32); }
    if ((t & 31) == 0) { int hd = t >> 5; asrc[(size_t)n * 4 + hd] = ps; adst[(size_t)n * 4 + hd] = pd; }
}

// ---------------- per-dst aggregation + softmax + bias + LN + ELU + residual ----------------
__global__ __launch_bounds__(128) void msg_kernel(
    const float* __restrict__ h, const float* __restrict__ asrc,
    const float* __restrict__ adst, const float* __restrict__ xres,
    const int* __restrict__ indptr, const int* __restrict__ eids,
    const int* __restrict__ srcarr, const float* __restrict__ ew,
    const float* __restrict__ ewsum,
    const float* __restrict__ Wedge, const float* __restrict__ aedge,
    const float* __restrict__ bias, const float* __restrict__ gamma,
    const float* __restrict__ beta, float* __restrict__ xout)
{
    const int n = blockIdx.x, t = threadIdx.x, hd = t >> 5;
    __shared__ float cL[4], adL[4], scL[4], dL[4];
    __shared__ int srcL[128];
    __shared__ float alL[128][4];
    __shared__ float r1[2], r2[2];

    // c[h] = dot(We_h, ae_h): a_eg[e,h] = ew[e]*c[h]
    float prod = Wedge[t] * aedge[t];
    #pragma unroll
    for (int o = 16; o; o >>= 1) prod += __shfl_down(prod, o, 32);
    if ((t & 31) == 0) cL[hd] = prod;
    if (t < 4) adL[t] = adst[(size_t)n * 4 + t];
    __syncthreads();

    const float ewm = ewsum[0] * (1.0f / N_EDGES);
    // self-loop folded into online-softmax initial state
    float mreg = 0.f, dreg = 0.f;
    if (t < 4) {
        float a0 = asrc[(size_t)n * 4 + t] + adL[t] + ewm * cL[t];
        a0 = a0 > 0.f ? a0 : NEG * a0;
        mreg = a0; dreg = 1.0f;
    }
    float acc = h[(size_t)n * DH + t];   // exp(alpha_self - m) = 1 at init

    const int st = indptr[n], en = indptr[n + 1];
    for (int base = st; base < en; base += 128) {
        const int cb = min(128, en - base);
        __syncthreads();   // protect LDS reuse across chunks
        if (t < cb) {
            const int eid = eids[base + t];
            const int s = srcarr[eid];
            const float wgt = ew[eid];
            srcL[t] = s;
            const float4 a4 = *(const float4*)(asrc + (size_t)s * 4);
            float v0 = a4.x + adL[0] + wgt * cL[0];
            float v1 = a4.y + adL[1] + wgt * cL[1];
            float v2 = a4.z + adL[2] + wgt * cL[2];
            float v3 = a4.w + adL[3] + wgt * cL[3];
            alL[t][0] = v0 > 0.f ? v0 : NEG * v0;
            alL[t][1] = v1 > 0.f ? v1 : NEG * v1;
            alL[t][2] = v2 > 0.f ? v2 : NEG * v2;
            alL[t][3] = v3 > 0.f ? v3 : NEG * v3;
        }
        __syncthreads();
        if (t < 4) {   // sequential online-softmax bookkeeping, one thread per head
            float chm = mreg;
            for (int j = 0; j < cb; ++j) chm = fmaxf(chm, alL[j][t]);
            const float sc = __expf(mreg - chm);
            float ds = dreg * sc;
            for (int j = 0; j < cb; ++j) {
                const float p = __expf(alL[j][t] - chm);
                alL[j][t] = p;
                ds += p;
            }
            mreg = chm; dreg = ds;
            scL[t] = sc;
        }
        __syncthreads();
        float a = acc * scL[hd];
        for (int j = 0; j < cb; ++j)
            a = fmaf(alL[j][hd], h[(size_t)srcL[j] * DH + t], a);
        acc = a;
    }
    if (t < 4) dL[t] = dreg;
    __syncthreads();

    float y = acc / (dL[hd] + 1e-16f) + bias[t];

    // LayerNorm over 128 channels + ELU + residual
    float s1 = y, s2 = y * y;
    #pragma unroll
    for (int o = 32; o; o >>= 1) { s1 += __shfl_down(s1, o, 64); s2 += __shfl_down(s2, o, 64); }
    if ((t & 63) == 0) { r1[t >> 6] = s1; r2[t >> 6] = s2; }
    __syncthreads();
    const float mu = (r1[0] + r1[1]) * (1.0f / DH);
    const float var = (r2[0] + r2[1]) * (1.0f / DH) - mu * mu;
    const float rs = rsqrtf(var + 1e-5f);
    float z = (y - mu) * rs * gamma[t] + beta[t];
    z = z > 0.f ? z : __expf(z) - 1.0f;
    xout[(size_t)n * DH + t] = z + xres[(size_t)n * DH + t];
}

// ---------------- global mean pool ----------------
#define PNODES 512
__global__ __launch_bounds__(128) void pool_kernel(const float* __restrict__ x,
        const int* __restrict__ batch, float* __restrict__ pool, int* __restrict__ gcnt)
{
    int t = threadIdx.x;
    int n0 = blockIdx.x * PNODES;
    int n1 = min(n0 + PNODES, N_NODES);
    float acc = 0.f; int cn = 0;
    int curb = batch[n0];
    for (int n = n0; n < n1; ++n) {
        int b = batch[n];
        if (b != curb) {
            atomicAdd(&pool[(size_t)curb * DH + t], acc);
            if (t == 0) atomicAdd(&gcnt[curb], cn);
            acc = 0.f; cn = 0; curb = b;
        }
        acc += x[(size_t)n * DH + t];
        ++cn;
    }
    atomicAdd(&pool[(size_t)curb * DH + t], acc);
    if (t == 0) atomicAdd(&gcnt[curb], cn);
}

__global__ void div_kernel(const float* __restrict__ pool, const int* __restrict__ gcnt,
                           float* __restrict__ out)
{
    int i = blockIdx.x * blockDim.x + threadIdx.x;
    if (i < NB * DH) {
        float c = (float)gcnt[i >> 7];
        out[i] = pool[i] / fmaxf(c, 1.0f);
    }
}

// ---------------- launch ----------------
extern "C" void kernel_launch(void* const* d_in, const int* in_sizes, int n_in,
                              void* d_out, int out_size, void* d_ws, size_t ws_size,
                              hipStream_t stream)
{
    const float* nf    = (const float*)d_in[0];
    const int*   esrc  = (const int*)d_in[1];
    const int*   edst  = esrc + N_EDGES;
    const float* ew    = (const float*)d_in[2];
    const int*   batch = (const int*)d_in[3];
    const float* Wp    = (const float*)d_in[4];
    const float* bp    = (const float*)d_in[5];
    const float* Wl[2]  = {(const float*)d_in[6],  (const float*)d_in[14]};
    const float* asl[2] = {(const float*)d_in[7],  (const float*)d_in[15]};
    const float* adl[2] = {(const float*)d_in[8],  (const float*)d_in[16]};
    const float* Wel[2] = {(const float*)d_in[9],  (const float*)d_in[17]};
    const float* ael[2] = {(const float*)d_in[10], (const float*)d_in[18]};
    const float* bl[2]  = {(const float*)d_in[11], (const float*)d_in[19]};
    const float* gl[2]  = {(const float*)d_in[12], (const float*)d_in[20]};
    const float* bel[2] = {(const float*)d_in[13], (const float*)d_in[21]};
    float* outp = (float*)d_out;

    char* w = (char*)d_ws;
    auto alloc = [&](size_t bytes) { char* p = w; w += (bytes + 255) & ~255ull; return p; };
    float* xA     = (float*)alloc((size_t)N_NODES * DH * 4);
    float* xB     = (float*)alloc((size_t)N_NODES * DH * 4);
    float* hbuf   = (float*)alloc((size_t)N_NODES * DH * 4);
    float* asrc   = (float*)alloc((size_t)N_NODES * 4 * 4);
    float* adst   = (float*)alloc((size_t)N_NODES * 4 * 4);
    float* pool   = (float*)alloc((size_t)NB * DH * 4);
    float* ews    = (float*)alloc(256);
    int* cnt      = (int*)alloc((size_t)N_NODES * 4);
    int* scanned  = (int*)alloc((size_t)N_NODES * 4);
    int* bsums    = (int*)alloc(1024);
    int* ptr      = (int*)alloc((size_t)(N_NODES + 8) * 4);
    int* cursor   = (int*)alloc((size_t)N_NODES * 4);
    int* gcnt     = (int*)alloc(256);
    int* eids     = (int*)alloc((size_t)N_EDGES * 4);

    hipMemsetAsync(ews, 0, 4, stream);
    hipMemsetAsync(cnt, 0, (size_t)N_NODES * 4, stream);
    hipMemsetAsync(pool, 0, (size_t)NB * DH * 4, stream);
    hipMemsetAsync(gcnt, 0, 256, stream);

    const int eb = (N_EDGES + 255) / 256;
    const int sb = (N_NODES + 255) / 256;  // 196

    ewsum_kernel<<<104, 256, 0, stream>>>(ew, ews);
    hist_kernel<<<eb, 256, 0, stream>>>(edst, cnt);
    scan_a<<<sb, 256, 0, stream>>>(cnt, scanned, bsums);
    scan_b<<<1, 256, 0, stream>>>(bsums, sb);
    scan_c<<<sb, 256, 0, stream>>>(scanned, bsums, cnt, ptr, cursor);
    fill_kernel<<<eb, 256, 0, stream>>>(edst, cursor, eids);

    gemm_kernel<DIN><<<(N_NODES + 63) / 64, 256, 0, stream>>>(nf, Wp, bp, xA, N_NODES);

    const float* xin = xA;
    float* xout = xB;
    for (int l = 0; l < 2; ++l) {
        gemm_kernel<DH><<<(N_NODES + 63) / 64, 256, 0, stream>>>(xin, Wl[l], nullptr, hbuf, N_NODES);
        att_kernel<<<N_NODES, 128, 0, stream>>>(hbuf, asl[l], adl[l], asrc, adst);
        msg_kernel<<<N_NODES, 128, 0, stream>>>(hbuf, asrc, adst, xin, ptr, eids, esrc, ew, ews,
                                                Wel[l], ael[l], bl[l], gl[l], bel[l], xout);
        float* tmp = (float*)xin; xin = xout; xout = tmp;
    }

    pool_kernel<<<(N_NODES + PNODES - 1) / PNODES, 128, 0, stream>>>(xin, batch, pool, gcnt);
    div_kernel<<<(NB * DH + 255) / 256, 256, 0, stream>>>(pool, gcnt, outp);
}

// Round 3
// 640.488 us; speedup vs baseline: 1.4425x; 1.1930x over previous
//
#include <hip/hip_runtime.h>

#define N_NODES 50000
#define N_EDGES 800000
#define DIN 384
#define DH 128
#define NB 64
#define NEG 0.2f

// ---------------- edge-weight sum (for self-loop fill value) ----------------
__global__ __launch_bounds__(256) void ewsum_kernel(const float* __restrict__ ew,
                                                    float* __restrict__ out) {
    __shared__ float sred[4];
    const int tid = threadIdx.x;
    float v = 0.0f;
    for (int i = blockIdx.x * 256 + tid; i < N_EDGES; i += gridDim.x * 256)
        v += ew[i];
    #pragma unroll
    for (int o = 32; o; o >>= 1) v += __shfl_down(v, o, 64);
    if ((tid & 63) == 0) sred[tid >> 6] = v;
    __syncthreads();
    if (tid == 0) atomicAdd(out, sred[0] + sred[1] + sred[2] + sred[3]);
}

// ---------------- CSR build: histogram, scan, fill ----------------
__global__ void hist_kernel(const int* __restrict__ dst, int* __restrict__ cnt) {
    int e = blockIdx.x * blockDim.x + threadIdx.x;
    if (e < N_EDGES) atomicAdd(&cnt[dst[e]], 1);
}

__global__ void scan_a(const int* __restrict__ cnt, int* __restrict__ scanned,
                       int* __restrict__ bsums) {
    __shared__ int s[256];
    int tid = threadIdx.x;
    int i = blockIdx.x * 256 + tid;
    int v = (i < N_NODES) ? cnt[i] : 0;
    s[tid] = v; __syncthreads();
    for (int o = 1; o < 256; o <<= 1) {
        int t = (tid >= o) ? s[tid - o] : 0;
        __syncthreads();
        s[tid] += t;
        __syncthreads();
    }
    if (i < N_NODES) scanned[i] = s[tid] - v;  // exclusive
    if (tid == 255) bsums[blockIdx.x] = s[255];
}

__global__ void scan_b(int* __restrict__ bsums, int nb) {
    __shared__ int s[256];
    int tid = threadIdx.x;
    int v = (tid < nb) ? bsums[tid] : 0;
    s[tid] = v; __syncthreads();
    for (int o = 1; o < 256; o <<= 1) {
        int t = (tid >= o) ? s[tid - o] : 0;
        __syncthreads();
        s[tid] += t;
        __syncthreads();
    }
    if (tid < nb) bsums[tid] = s[tid] - v;  // exclusive
}

__global__ void scan_c(const int* __restrict__ scanned, const int* __restrict__ bsums,
                       const int* __restrict__ cnt, int* __restrict__ ptr,
                       int* __restrict__ cursor) {
    int i = blockIdx.x * 256 + threadIdx.x;
    if (i < N_NODES) {
        int p = scanned[i] + bsums[blockIdx.x];
        ptr[i] = p;
        cursor[i] = p;
        if (i == N_NODES - 1) ptr[N_NODES] = p + cnt[i];
    }
}

__global__ void fill_kernel(const int* __restrict__ dst, int* __restrict__ cursor,
                            int* __restrict__ eids) {
    int e = blockIdx.x * blockDim.x + threadIdx.x;
    if (e < N_EDGES) {
        int p = atomicAdd(&cursor[dst[e]], 1);
        eids[p] = e;
    }
}

// ---------------- fp32 GEMM: C[M,128] = A[M,K] @ W[K,128] (+bias) ----------------
template<int K>
__global__ __launch_bounds__(256) void gemm_kernel(const float* __restrict__ A,
                                                   const float* __restrict__ W,
                                                   const float* __restrict__ bias,
                                                   float* __restrict__ C, int M)
{
    __shared__ float As[8][64];     // [k][m]
    __shared__ float Ws[8][DH];     // [k][n]
    const int tid = threadIdx.x;
    const int tx = tid & 31;        // 32 threads across N, 4 cols each
    const int ty = tid >> 5;        // 8 thread-rows, 8 rows each
    const int m0 = blockIdx.x * 64;
    const int lr = tid >> 2;        // load: row within A tile
    const int lk = (tid & 3) * 2;   // load: k pair
    const int wk = tid >> 5;        // load: W tile k
    const int wc = (tid & 31) * 4;  // load: W tile col
    float acc[8][4] = {};
    int arow = m0 + lr; if (arow >= M) arow = M - 1;
    const float* Aptr = A + (size_t)arow * K + lk;

    for (int k0 = 0; k0 < K; k0 += 8) {
        float2 av = *(const float2*)(Aptr + k0);
        float4 wv = *(const float4*)(W + (size_t)(k0 + wk) * DH + wc);
        As[lk][lr] = av.x; As[lk + 1][lr] = av.y;
        *(float4*)&Ws[wk][wc] = wv;
        __syncthreads();
        #pragma unroll
        for (int k = 0; k < 8; ++k) {
            float a[8];
            *(float4*)&a[0] = *(const float4*)&As[k][ty * 8];
            *(float4*)&a[4] = *(const float4*)&As[k][ty * 8 + 4];
            float4 wf = *(const float4*)&Ws[k][tx * 4];
            #pragma unroll
            for (int r = 0; r < 8; ++r) {
                acc[r][0] = fmaf(a[r], wf.x, acc[r][0]);
                acc[r][1] = fmaf(a[r], wf.y, acc[r][1]);
                acc[r][2] = fmaf(a[r], wf.z, acc[r][2]);
                acc[r][3] = fmaf(a[r], wf.w, acc[r][3]);
            }
        }
        __syncthreads();
    }
    float4 bv = {0.f, 0.f, 0.f, 0.f};
    if (bias) bv = *(const float4*)(bias + tx * 4);
    #pragma unroll
    for (int r = 0; r < 8; ++r) {
        int row = m0 + ty * 8 + r;
        if (row < M) {
            float4 o;
            o.x = acc[r][0] + bv.x; o.y = acc[r][1] + bv.y;
            o.z = acc[r][2] + bv.z; o.w = acc[r][3] + bv.w;
            *(float4*)(C + (size_t)row * DH + tx * 4) = o;
        }
    }
}

// ---------------- per-node attention logits a_src, a_dst ----------------
__global__ __launch_bounds__(128) void att_kernel(const float* __restrict__ h,
        const float* __restrict__ a_s, const float* __restrict__ a_d,
        float* __restrict__ asrc, float* __restrict__ adst)
{
    int n = blockIdx.x, t = threadIdx.x;
    float v = h[(size_t)n * DH + t];
    float ps = v * a_s[t], pd = v * a_d[t];
    #pragma unroll
    for (int o = 16; o; o >>= 1) { ps += __shfl_down(ps, o, 32); pd += __shfl_down(pd, o, 32); }
    if ((t & 31) == 0) { int hd = t >> 5; asrc[(size_t)n * 4 + hd] = ps; adst[(size_t)n * 4 + hd] = pd; }
}

// ---------------- per-dst aggregation + softmax + bias + LN + ELU + residual ----------------
__global__ __launch_bounds__(128) void msg_kernel(
    const float* __restrict__ h, const float* __restrict__ asrc,
    const float* __restrict__ adst, const float* __restrict__ xres,
    const int* __restrict__ indptr, const int* __restrict__ eids,
    const int* __restrict__ srcarr, const float* __restrict__ ew,
    const float* __restrict__ ewsum,
    const float* __restrict__ Wedge, const float* __restrict__ aedge,
    const float* __restrict__ bias, const float* __restrict__ gamma,
    const float* __restrict__ beta, float* __restrict__ xout)
{
    const int n = blockIdx.x, t = threadIdx.x, hd = t >> 5;
    __shared__ float cL[4], adL[4], scL[4], dL[4];
    __shared__ int srcL[128];
    __shared__ float alL[128][4];
    __shared__ float r1[2], r2[2];

    // c[h] = dot(We_h, ae_h): a_eg[e,h] = ew[e]*c[h]
    float prod = Wedge[t] * aedge[t];
    #pragma unroll
    for (int o = 16; o; o >>= 1) prod += __shfl_down(prod, o, 32);
    if ((t & 31) == 0) cL[hd] = prod;
    if (t < 4) adL[t] = adst[(size_t)n * 4 + t];
    __syncthreads();

    const float ewm = ewsum[0] * (1.0f / N_EDGES);
    // self-loop folded into online-softmax initial state
    float mreg = 0.f, dreg = 0.f;
    if (t < 4) {
        float a0 = asrc[(size_t)n * 4 + t] + adL[t] + ewm * cL[t];
        a0 = a0 > 0.f ? a0 : NEG * a0;
        mreg = a0; dreg = 1.0f;
    }
    float acc = h[(size_t)n * DH + t];   // exp(alpha_self - m) = 1 at init

    const int st = indptr[n], en = indptr[n + 1];
    for (int base = st; base < en; base += 128) {
        const int cb = min(128, en - base);
        __syncthreads();   // protect LDS reuse across chunks
        if (t < cb) {
            const int eid = eids[base + t];
            const int s = srcarr[eid];
            const float wgt = ew[eid];
            srcL[t] = s;
            const float4 a4 = *(const float4*)(asrc + (size_t)s * 4);
            float v0 = a4.x + adL[0] + wgt * cL[0];
            float v1 = a4.y + adL[1] + wgt * cL[1];
            float v2 = a4.z + adL[2] + wgt * cL[2];
            float v3 = a4.w + adL[3] + wgt * cL[3];
            alL[t][0] = v0 > 0.f ? v0 : NEG * v0;
            alL[t][1] = v1 > 0.f ? v1 : NEG * v1;
            alL[t][2] = v2 > 0.f ? v2 : NEG * v2;
            alL[t][3] = v3 > 0.f ? v3 : NEG * v3;
        }
        __syncthreads();
        if (t < 4) {   // sequential online-softmax bookkeeping, one thread per head
            float chm = mreg;
            for (int j = 0; j < cb; ++j) chm = fmaxf(chm, alL[j][t]);
            const float sc = __expf(mreg - chm);
            float ds = dreg * sc;
            for (int j = 0; j < cb; ++j) {
                const float p = __expf(alL[j][t] - chm);
                alL[j][t] = p;
                ds += p;
            }
            mreg = chm; dreg = ds;
            scL[t] = sc;
        }
        __syncthreads();
        float a = acc * scL[hd];
        for (int j = 0; j < cb; ++j)
            a = fmaf(alL[j][hd], h[(size_t)srcL[j] * DH + t], a);
        acc = a;
    }
    if (t < 4) dL[t] = dreg;
    __syncthreads();

    float y = acc / (dL[hd] + 1e-16f) + bias[t];

    // LayerNorm over 128 channels + ELU + residual
    float s1 = y, s2 = y * y;
    #pragma unroll
    for (int o = 32; o; o >>= 1) { s1 += __shfl_down(s1, o, 64); s2 += __shfl_down(s2, o, 64); }
    if ((t & 63) == 0) { r1[t >> 6] = s1; r2[t >> 6] = s2; }
    __syncthreads();
    const float mu = (r1[0] + r1[1]) * (1.0f / DH);
    const float var = (r2[0] + r2[1]) * (1.0f / DH) - mu * mu;
    const float rs = rsqrtf(var + 1e-5f);
    float z = (y - mu) * rs * gamma[t] + beta[t];
    z = z > 0.f ? z : __expf(z) - 1.0f;
    xout[(size_t)n * DH + t] = z + xres[(size_t)n * DH + t];
}

// ---------------- global mean pool ----------------
// PNODES=64 -> 782 blocks (~6 waves/CU). Was PNODES=512 (98 blocks, 2%
// occupancy, serial latency-bound: 142 us for a 25.6 MB read).
#define PNODES 64
__global__ __launch_bounds__(128) void pool_kernel(const float* __restrict__ x,
        const int* __restrict__ batch, float* __restrict__ pool, int* __restrict__ gcnt)
{
    int t = threadIdx.x;
    int n0 = blockIdx.x * PNODES;
    if (n0 >= N_NODES) return;
    int n1 = min(n0 + PNODES, N_NODES);
    float acc = 0.f; int cn = 0;
    int curb = batch[n0];
    for (int n = n0; n < n1; ++n) {
        int b = batch[n];
        if (b != curb) {
            atomicAdd(&pool[(size_t)curb * DH + t], acc);
            if (t == 0) atomicAdd(&gcnt[curb], cn);
            acc = 0.f; cn = 0; curb = b;
        }
        acc += x[(size_t)n * DH + t];
        ++cn;
    }
    atomicAdd(&pool[(size_t)curb * DH + t], acc);
    if (t == 0) atomicAdd(&gcnt[curb], cn);
}

__global__ void div_kernel(const float* __restrict__ pool, const int* __restrict__ gcnt,
                           float* __restrict__ out)
{
    int i = blockIdx.x * blockDim.x + threadIdx.x;
    if (i < NB * DH) {
        float c = (float)gcnt[i >> 7];
        out[i] = pool[i] / fmaxf(c, 1.0f);
    }
}

// ---------------- launch ----------------
extern "C" void kernel_launch(void* const* d_in, const int* in_sizes, int n_in,
                              void* d_out, int out_size, void* d_ws, size_t ws_size,
                              hipStream_t stream)
{
    const float* nf    = (const float*)d_in[0];
    const int*   esrc  = (const int*)d_in[1];
    const int*   edst  = esrc + N_EDGES;
    const float* ew    = (const float*)d_in[2];
    const int*   batch = (const int*)d_in[3];
    const float* Wp    = (const float*)d_in[4];
    const float* bp    = (const float*)d_in[5];
    const float* Wl[2]  = {(const float*)d_in[6],  (const float*)d_in[14]};
    const float* asl[2] = {(const float*)d_in[7],  (const float*)d_in[15]};
    const float* adl[2] = {(const float*)d_in[8],  (const float*)d_in[16]};
    const float* Wel[2] = {(const float*)d_in[9],  (const float*)d_in[17]};
    const float* ael[2] = {(const float*)d_in[10], (const float*)d_in[18]};
    const float* bl[2]  = {(const float*)d_in[11], (const float*)d_in[19]};
    const float* gl[2]  = {(const float*)d_in[12], (const float*)d_in[20]};
    const float* bel[2] = {(const float*)d_in[13], (const float*)d_in[21]};
    float* outp = (float*)d_out;

    char* w = (char*)d_ws;
    auto alloc = [&](size_t bytes) { char* p = w; w += (bytes + 255) & ~255ull; return p; };
    float* xA     = (float*)alloc((size_t)N_NODES * DH * 4);
    float* xB     = (float*)alloc((size_t)N_NODES * DH * 4);
    float* hbuf   = (float*)alloc((size_t)N_NODES * DH * 4);
    float* asrc   = (float*)alloc((size_t)N_NODES * 4 * 4);
    float* adst   = (float*)alloc((size_t)N_NODES * 4 * 4);
    float* pool   = (float*)alloc((size_t)NB * DH * 4);
    float* ews    = (float*)alloc(256);
    int* cnt      = (int*)alloc((size_t)N_NODES * 4);
    int* scanned  = (int*)alloc((size_t)N_NODES * 4);
    int* bsums    = (int*)alloc(1024);
    int* ptr      = (int*)alloc((size_t)(N_NODES + 8) * 4);
    int* cursor   = (int*)alloc((size_t)N_NODES * 4);
    int* gcnt     = (int*)alloc(256);
    int* eids     = (int*)alloc((size_t)N_EDGES * 4);

    hipMemsetAsync(ews, 0, 4, stream);
    hipMemsetAsync(cnt, 0, (size_t)N_NODES * 4, stream);
    hipMemsetAsync(pool, 0, (size_t)NB * DH * 4, stream);
    hipMemsetAsync(gcnt, 0, 256, stream);

    const int eb = (N_EDGES + 255) / 256;
    const int sb = (N_NODES + 255) / 256;  // 196

    ewsum_kernel<<<104, 256, 0, stream>>>(ew, ews);
    hist_kernel<<<eb, 256, 0, stream>>>(edst, cnt);
    scan_a<<<sb, 256, 0, stream>>>(cnt, scanned, bsums);
    scan_b<<<1, 256, 0, stream>>>(bsums, sb);
    scan_c<<<sb, 256, 0, stream>>>(scanned, bsums, cnt, ptr, cursor);
    fill_kernel<<<eb, 256, 0, stream>>>(edst, cursor, eids);

    gemm_kernel<DIN><<<(N_NODES + 63) / 64, 256, 0, stream>>>(nf, Wp, bp, xA, N_NODES);

    const float* xin = xA;
    float* xout = xB;
    for (int l = 0; l < 2; ++l) {
        gemm_kernel<DH><<<(N_NODES + 63) / 64, 256, 0, stream>>>(xin, Wl[l], nullptr, hbuf, N_NODES);
        att_kernel<<<N_NODES, 128, 0, stream>>>(hbuf, asl[l], adl[l], asrc, adst);
        msg_kernel<<<N_NODES, 128, 0, stream>>>(hbuf, asrc, adst, xin, ptr, eids, esrc, ew, ews,
                                                Wel[l], ael[l], bl[l], gl[l], bel[l], xout);
        float* tmp = (float*)xin; xin = xout; xout = tmp;
    }

    pool_kernel<<<(N_NODES + PNODES - 1) / PNODES, 128, 0, stream>>>(xin, batch, pool, gcnt);
    div_kernel<<<(NB * DH + 255) / 256, 256, 0, stream>>>(pool, gcnt, outp);
}

// Round 4
// 579.457 us; speedup vs baseline: 1.5944x; 1.1053x over previous
//
#include <hip/hip_runtime.h>

#define N_NODES 50000
#define N_EDGES 800000
#define DIN 384
#define DH 128
#define NB 64
#define NEG 0.2f

// ---------------- bf16 helpers (exact bit ops) ----------------
__device__ __forceinline__ float bf2f(unsigned short u) {
    return __uint_as_float((unsigned)u << 16);
}
__device__ __forceinline__ unsigned short f2bf(float x) {  // RNE
    unsigned u = __float_as_uint(x);
    return (unsigned short)((u + 0x7fff + ((u >> 16) & 1)) >> 16);
}
__device__ __forceinline__ float4 bf4_to_f4(const unsigned short* p) {
    ushort4 u = *(const ushort4*)p;
    float4 f;
    f.x = bf2f(u.x); f.y = bf2f(u.y); f.z = bf2f(u.z); f.w = bf2f(u.w);
    return f;
}

// ---------------- edge-weight sum (for self-loop fill value) ----------------
__global__ __launch_bounds__(256) void ewsum_kernel(const float* __restrict__ ew,
                                                    float* __restrict__ out) {
    __shared__ float sred[4];
    const int tid = threadIdx.x;
    float v = 0.0f;
    for (int i = blockIdx.x * 256 + tid; i < N_EDGES; i += gridDim.x * 256)
        v += ew[i];
    #pragma unroll
    for (int o = 32; o; o >>= 1) v += __shfl_down(v, o, 64);
    if ((tid & 63) == 0) sred[tid >> 6] = v;
    __syncthreads();
    if (tid == 0) atomicAdd(out, sred[0] + sred[1] + sred[2] + sred[3]);
}

// ---------------- CSR build: histogram, scan, fill ----------------
__global__ void hist_kernel(const int* __restrict__ dst, int* __restrict__ cnt) {
    int e = blockIdx.x * blockDim.x + threadIdx.x;
    if (e < N_EDGES) atomicAdd(&cnt[dst[e]], 1);
}

__global__ void scan_a(const int* __restrict__ cnt, int* __restrict__ scanned,
                       int* __restrict__ bsums) {
    __shared__ int s[256];
    int tid = threadIdx.x;
    int i = blockIdx.x * 256 + tid;
    int v = (i < N_NODES) ? cnt[i] : 0;
    s[tid] = v; __syncthreads();
    for (int o = 1; o < 256; o <<= 1) {
        int t = (tid >= o) ? s[tid - o] : 0;
        __syncthreads();
        s[tid] += t;
        __syncthreads();
    }
    if (i < N_NODES) scanned[i] = s[tid] - v;  // exclusive
    if (tid == 255) bsums[blockIdx.x] = s[255];
}

__global__ void scan_b(int* __restrict__ bsums, int nb) {
    __shared__ int s[256];
    int tid = threadIdx.x;
    int v = (tid < nb) ? bsums[tid] : 0;
    s[tid] = v; __syncthreads();
    for (int o = 1; o < 256; o <<= 1) {
        int t = (tid >= o) ? s[tid - o] : 0;
        __syncthreads();
        s[tid] += t;
        __syncthreads();
    }
    if (tid < nb) bsums[tid] = s[tid] - v;  // exclusive
}

__global__ void scan_c(const int* __restrict__ scanned, const int* __restrict__ bsums,
                       const int* __restrict__ cnt, int* __restrict__ ptr,
                       int* __restrict__ cursor) {
    int i = blockIdx.x * 256 + threadIdx.x;
    if (i < N_NODES) {
        int p = scanned[i] + bsums[blockIdx.x];
        ptr[i] = p;
        cursor[i] = p;
        if (i == N_NODES - 1) ptr[N_NODES] = p + cnt[i];
    }
}

__global__ void fill_kernel(const int* __restrict__ dst, int* __restrict__ cursor,
                            int* __restrict__ eids) {
    int e = blockIdx.x * blockDim.x + threadIdx.x;
    if (e < N_EDGES) {
        int p = atomicAdd(&cursor[dst[e]], 1);
        eids[p] = e;
    }
}

// ---------------- fp32 GEMM: C[M,128] = A[M,K] @ W[K,128] (+bias) ----------------
// BF16OUT: write bf16 rows (halves gather traffic in the downstream msg kernel).
template<int K, bool BF16OUT>
__global__ __launch_bounds__(256) void gemm_kernel(const float* __restrict__ A,
                                                   const float* __restrict__ W,
                                                   const float* __restrict__ bias,
                                                   void* __restrict__ Cv, int M)
{
    __shared__ float As[8][64];     // [k][m]
    __shared__ float Ws[8][DH];     // [k][n]
    const int tid = threadIdx.x;
    const int tx = tid & 31;        // 32 threads across N, 4 cols each
    const int ty = tid >> 5;        // 8 thread-rows, 8 rows each
    const int m0 = blockIdx.x * 64;
    const int lr = tid >> 2;        // load: row within A tile
    const int lk = (tid & 3) * 2;   // load: k pair
    const int wk = tid >> 5;        // load: W tile k
    const int wc = (tid & 31) * 4;  // load: W tile col
    float acc[8][4] = {};
    int arow = m0 + lr; if (arow >= M) arow = M - 1;
    const float* Aptr = A + (size_t)arow * K + lk;

    for (int k0 = 0; k0 < K; k0 += 8) {
        float2 av = *(const float2*)(Aptr + k0);
        float4 wv = *(const float4*)(W + (size_t)(k0 + wk) * DH + wc);
        As[lk][lr] = av.x; As[lk + 1][lr] = av.y;
        *(float4*)&Ws[wk][wc] = wv;
        __syncthreads();
        #pragma unroll
        for (int k = 0; k < 8; ++k) {
            float a[8];
            *(float4*)&a[0] = *(const float4*)&As[k][ty * 8];
            *(float4*)&a[4] = *(const float4*)&As[k][ty * 8 + 4];
            float4 wf = *(const float4*)&Ws[k][tx * 4];
            #pragma unroll
            for (int r = 0; r < 8; ++r) {
                acc[r][0] = fmaf(a[r], wf.x, acc[r][0]);
                acc[r][1] = fmaf(a[r], wf.y, acc[r][1]);
                acc[r][2] = fmaf(a[r], wf.z, acc[r][2]);
                acc[r][3] = fmaf(a[r], wf.w, acc[r][3]);
            }
        }
        __syncthreads();
    }
    float4 bv = {0.f, 0.f, 0.f, 0.f};
    if (bias) bv = *(const float4*)(bias + tx * 4);
    #pragma unroll
    for (int r = 0; r < 8; ++r) {
        int row = m0 + ty * 8 + r;
        if (row < M) {
            float x0 = acc[r][0] + bv.x, x1 = acc[r][1] + bv.y;
            float x2 = acc[r][2] + bv.z, x3 = acc[r][3] + bv.w;
            if constexpr (BF16OUT) {
                unsigned short* C = (unsigned short*)Cv;
                ushort4 o;
                o.x = f2bf(x0); o.y = f2bf(x1); o.z = f2bf(x2); o.w = f2bf(x3);
                *(ushort4*)(C + (size_t)row * DH + tx * 4) = o;
            } else {
                float* C = (float*)Cv;
                float4 o = {x0, x1, x2, x3};
                *(float4*)(C + (size_t)row * DH + tx * 4) = o;
            }
        }
    }
}

// ---------------- per-node attention logits a_src, a_dst (bf16 h) ----------------
__global__ __launch_bounds__(128) void att_kernel(const unsigned short* __restrict__ h,
        const float* __restrict__ a_s, const float* __restrict__ a_d,
        float* __restrict__ asrc, float* __restrict__ adst)
{
    int n = blockIdx.x, t = threadIdx.x;
    float v = bf2f(h[(size_t)n * DH + t]);
    float ps = v * a_s[t], pd = v * a_d[t];
    #pragma unroll
    for (int o = 16; o; o >>= 1) { ps += __shfl_down(ps, o, 32); pd += __shfl_down(pd, o, 32); }
    if ((t & 31) == 0) { int hd = t >> 5; asrc[(size_t)n * 4 + hd] = ps; adst[(size_t)n * 4 + hd] = pd; }
}

// ---------------- msg: one wave per node ----------------
// Lane l = (sub = l>>5, c4 = l&31): covers channels 4*c4..4*c4+3, edge-parity sub.
// Parallel online-softmax (butterfly reductions) + 2-edges-per-step bf16x4 gather.
__global__ __launch_bounds__(64) void msg_kernel(
    const unsigned short* __restrict__ h, const float* __restrict__ asrc,
    const float* __restrict__ adst, const float* __restrict__ xres,
    const int* __restrict__ indptr, const int* __restrict__ eids,
    const int* __restrict__ srcarr, const float* __restrict__ ew,
    const float* __restrict__ ewsum,
    const float* __restrict__ Wedge, const float* __restrict__ aedge,
    const float* __restrict__ bias, const float* __restrict__ gamma,
    const float* __restrict__ beta, float* __restrict__ xout)
{
    const int n = blockIdx.x, l = threadIdx.x;
    const int sub = l >> 5, c4 = l & 31, hd = c4 >> 3;
    __shared__ float alL[64][4];
    __shared__ int srcS[64];

    // c[k] = dot(We_k, ae_k)  (a_eg[e,k] = ew[e]*c[k])
    float p0 = Wedge[l] * aedge[l];
    float p1 = Wedge[l + 64] * aedge[l + 64];
    #pragma unroll
    for (int o = 1; o < 32; o <<= 1) { p0 += __shfl_xor(p0, o, 64); p1 += __shfl_xor(p1, o, 64); }
    float cc[4];
    cc[0] = __shfl(p0, 0, 64);  cc[1] = __shfl(p0, 32, 64);
    cc[2] = __shfl(p1, 0, 64);  cc[3] = __shfl(p1, 32, 64);

    const float4 ad4 = *(const float4*)(adst + (size_t)n * 4);
    const float4 as4 = *(const float4*)(asrc + (size_t)n * 4);
    const float adv[4] = {ad4.x, ad4.y, ad4.z, ad4.w};
    const float asv[4] = {as4.x, as4.y, as4.z, as4.w};
    const float ewm = ewsum[0] * (1.0f / N_EDGES);

    // self-loop folded into initial online-softmax state
    float mreg[4], dreg[4];
    #pragma unroll
    for (int k = 0; k < 4; ++k) {
        float a0 = asv[k] + adv[k] + ewm * cc[k];
        a0 = a0 > 0.f ? a0 : NEG * a0;
        mreg[k] = a0; dreg[k] = 1.0f;
    }
    float4 acc = {0.f, 0.f, 0.f, 0.f};
    if (sub == 0) acc = bf4_to_f4(h + (size_t)n * DH + c4 * 4);  // exp(self-m)=1

    const int st = indptr[n], en = indptr[n + 1];
    for (int base = st; base < en; base += 64) {
        const int cb = min(64, en - base);
        const bool act = l < cb;
        float val[4];
        if (act) {
            const int eid = eids[base + l];
            const int s = srcarr[eid];
            const float wgt = ew[eid];
            srcS[l] = s;
            const float4 a4 = *(const float4*)(asrc + (size_t)s * 4);
            const float av[4] = {a4.x, a4.y, a4.z, a4.w};
            #pragma unroll
            for (int k = 0; k < 4; ++k) {
                float v = av[k] + adv[k] + wgt * cc[k];
                val[k] = v > 0.f ? v : NEG * v;
            }
        } else {
            val[0] = val[1] = val[2] = val[3] = -3.0e38f;
        }
        float mx[4] = {val[0], val[1], val[2], val[3]};
        #pragma unroll
        for (int o = 1; o < 64; o <<= 1) {
            #pragma unroll
            for (int k = 0; k < 4; ++k) mx[k] = fmaxf(mx[k], __shfl_xor(mx[k], o, 64));
        }
        float sc[4], pv[4];
        #pragma unroll
        for (int k = 0; k < 4; ++k) {
            const float nm = fmaxf(mreg[k], mx[k]);
            sc[k] = __expf(mreg[k] - nm);
            pv[k] = act ? __expf(val[k] - nm) : 0.0f;
            mreg[k] = nm;
        }
        float4 pw = {pv[0], pv[1], pv[2], pv[3]};
        *(float4*)alL[l] = pw;
        float sm[4] = {pv[0], pv[1], pv[2], pv[3]};
        #pragma unroll
        for (int o = 1; o < 64; o <<= 1) {
            #pragma unroll
            for (int k = 0; k < 4; ++k) sm[k] += __shfl_xor(sm[k], o, 64);
        }
        #pragma unroll
        for (int k = 0; k < 4; ++k) dreg[k] = dreg[k] * sc[k] + sm[k];
        const float f = sc[hd];
        acc.x *= f; acc.y *= f; acc.z *= f; acc.w *= f;
        __syncthreads();  // single wave: cheap; guarantees LDS visibility

        const int half = (cb + 1) >> 1;
        for (int j = 0; j < half; ++j) {
            const int e = 2 * j + sub;
            if (e < cb) {
                const int s = srcS[e];
                const float coef = alL[e][hd];
                const float4 hv = bf4_to_f4(h + (size_t)s * DH + c4 * 4);
                acc.x = fmaf(coef, hv.x, acc.x);
                acc.y = fmaf(coef, hv.y, acc.y);
                acc.z = fmaf(coef, hv.z, acc.z);
                acc.w = fmaf(coef, hv.w, acc.w);
            }
        }
        __syncthreads();  // protect LDS reuse by next chunk
    }

    // combine edge-parity halves: lanes l and l^32 hold partial sums
    acc.x += __shfl_xor(acc.x, 32, 64);
    acc.y += __shfl_xor(acc.y, 32, 64);
    acc.z += __shfl_xor(acc.z, 32, 64);
    acc.w += __shfl_xor(acc.w, 32, 64);

    const float4 b4 = *(const float4*)(bias + c4 * 4);
    const float inv_d = 1.0f / (dreg[hd] + 1e-16f);
    float4 y;
    y.x = acc.x * inv_d + b4.x;
    y.y = acc.y * inv_d + b4.y;
    y.z = acc.z * inv_d + b4.z;
    y.w = acc.w * inv_d + b4.w;

    // LayerNorm over 128 channels (reduce over 32-lane half; halves identical)
    float s1 = y.x + y.y + y.z + y.w;
    float s2 = y.x * y.x + y.y * y.y + y.z * y.z + y.w * y.w;
    #pragma unroll
    for (int o = 1; o < 32; o <<= 1) {
        s1 += __shfl_xor(s1, o, 64);
        s2 += __shfl_xor(s2, o, 64);
    }
    const float mu = s1 * (1.0f / DH);
    const float var = s2 * (1.0f / DH) - mu * mu;
    const float rs = rsqrtf(var + 1e-5f);

    if (sub == 0) {
        const float4 g4 = *(const float4*)(gamma + c4 * 4);
        const float4 be4 = *(const float4*)(beta + c4 * 4);
        const float4 r4 = *(const float4*)(xres + (size_t)n * DH + c4 * 4);
        float4 z;
        z.x = (y.x - mu) * rs * g4.x + be4.x;
        z.y = (y.y - mu) * rs * g4.y + be4.y;
        z.z = (y.z - mu) * rs * g4.z + be4.z;
        z.w = (y.w - mu) * rs * g4.w + be4.w;
        z.x = (z.x > 0.f ? z.x : __expf(z.x) - 1.0f) + r4.x;
        z.y = (z.y > 0.f ? z.y : __expf(z.y) - 1.0f) + r4.y;
        z.z = (z.z > 0.f ? z.z : __expf(z.z) - 1.0f) + r4.z;
        z.w = (z.w > 0.f ? z.w : __expf(z.w) - 1.0f) + r4.w;
        *(float4*)(xout + (size_t)n * DH + c4 * 4) = z;
    }
}

// ---------------- global mean pool ----------------
#define PNODES 64
__global__ __launch_bounds__(128) void pool_kernel(const float* __restrict__ x,
        const int* __restrict__ batch, float* __restrict__ pool, int* __restrict__ gcnt)
{
    int t = threadIdx.x;
    int n0 = blockIdx.x * PNODES;
    if (n0 >= N_NODES) return;
    int n1 = min(n0 + PNODES, N_NODES);
    float acc = 0.f; int cn = 0;
    int curb = batch[n0];
    for (int n = n0; n < n1; ++n) {
        int b = batch[n];
        if (b != curb) {
            atomicAdd(&pool[(size_t)curb * DH + t], acc);
            if (t == 0) atomicAdd(&gcnt[curb], cn);
            acc = 0.f; cn = 0; curb = b;
        }
        acc += x[(size_t)n * DH + t];
        ++cn;
    }
    atomicAdd(&pool[(size_t)curb * DH + t], acc);
    if (t == 0) atomicAdd(&gcnt[curb], cn);
}

__global__ void div_kernel(const float* __restrict__ pool, const int* __restrict__ gcnt,
                           float* __restrict__ out)
{
    int i = blockIdx.x * blockDim.x + threadIdx.x;
    if (i < NB * DH) {
        float c = (float)gcnt[i >> 7];
        out[i] = pool[i] / fmaxf(c, 1.0f);
    }
}

// ---------------- launch ----------------
extern "C" void kernel_launch(void* const* d_in, const int* in_sizes, int n_in,
                              void* d_out, int out_size, void* d_ws, size_t ws_size,
                              hipStream_t stream)
{
    const float* nf    = (const float*)d_in[0];
    const int*   esrc  = (const int*)d_in[1];
    const int*   edst  = esrc + N_EDGES;
    const float* ew    = (const float*)d_in[2];
    const int*   batch = (const int*)d_in[3];
    const float* Wp    = (const float*)d_in[4];
    const float* bp    = (const float*)d_in[5];
    const float* Wl[2]  = {(const float*)d_in[6],  (const float*)d_in[14]};
    const float* asl[2] = {(const float*)d_in[7],  (const float*)d_in[15]};
    const float* adl[2] = {(const float*)d_in[8],  (const float*)d_in[16]};
    const float* Wel[2] = {(const float*)d_in[9],  (const float*)d_in[17]};
    const float* ael[2] = {(const float*)d_in[10], (const float*)d_in[18]};
    const float* bl[2]  = {(const float*)d_in[11], (const float*)d_in[19]};
    const float* gl[2]  = {(const float*)d_in[12], (const float*)d_in[20]};
    const float* bel[2] = {(const float*)d_in[13], (const float*)d_in[21]};
    float* outp = (float*)d_out;

    char* w = (char*)d_ws;
    auto alloc = [&](size_t bytes) { char* p = w; w += (bytes + 255) & ~255ull; return p; };
    float* xA     = (float*)alloc((size_t)N_NODES * DH * 4);
    float* xB     = (float*)alloc((size_t)N_NODES * DH * 4);
    unsigned short* hbuf = (unsigned short*)alloc((size_t)N_NODES * DH * 2);
    float* asrc   = (float*)alloc((size_t)N_NODES * 4 * 4);
    float* adst   = (float*)alloc((size_t)N_NODES * 4 * 4);
    float* pool   = (float*)alloc((size_t)NB * DH * 4);
    float* ews    = (float*)alloc(256);
    int* cnt      = (int*)alloc((size_t)N_NODES * 4);
    int* scanned  = (int*)alloc((size_t)N_NODES * 4);
    int* bsums    = (int*)alloc(1024);
    int* ptr      = (int*)alloc((size_t)(N_NODES + 8) * 4);
    int* cursor   = (int*)alloc((size_t)N_NODES * 4);
    int* gcnt     = (int*)alloc(256);
    int* eids     = (int*)alloc((size_t)N_EDGES * 4);

    hipMemsetAsync(ews, 0, 4, stream);
    hipMemsetAsync(cnt, 0, (size_t)N_NODES * 4, stream);
    hipMemsetAsync(pool, 0, (size_t)NB * DH * 4, stream);
    hipMemsetAsync(gcnt, 0, 256, stream);

    const int eb = (N_EDGES + 255) / 256;
    const int sb = (N_NODES + 255) / 256;  // 196

    ewsum_kernel<<<104, 256, 0, stream>>>(ew, ews);
    hist_kernel<<<eb, 256, 0, stream>>>(edst, cnt);
    scan_a<<<sb, 256, 0, stream>>>(cnt, scanned, bsums);
    scan_b<<<1, 256, 0, stream>>>(bsums, sb);
    scan_c<<<sb, 256, 0, stream>>>(scanned, bsums, cnt, ptr, cursor);
    fill_kernel<<<eb, 256, 0, stream>>>(edst, cursor, eids);

    gemm_kernel<DIN, false><<<(N_NODES + 63) / 64, 256, 0, stream>>>(nf, Wp, bp, xA, N_NODES);

    const float* xin = xA;
    float* xout = xB;
    for (int l = 0; l < 2; ++l) {
        gemm_kernel<DH, true><<<(N_NODES + 63) / 64, 256, 0, stream>>>(xin, Wl[l], nullptr, hbuf, N_NODES);
        att_kernel<<<N_NODES, 128, 0, stream>>>(hbuf, asl[l], adl[l], asrc, adst);
        msg_kernel<<<N_NODES, 64, 0, stream>>>(hbuf, asrc, adst, xin, ptr, eids, esrc, ew, ews,
                                               Wel[l], ael[l], bl[l], gl[l], bel[l], xout);
        float* tmp = (float*)xin; xin = xout; xout = tmp;
    }

    pool_kernel<<<(N_NODES + PNODES - 1) / PNODES, 128, 0, stream>>>(xin, batch, pool, gcnt);
    div_kernel<<<(NB * DH + 255) / 256, 256, 0, stream>>>(pool, gcnt, outp);
}

// Round 5
// 492.142 us; speedup vs baseline: 1.8773x; 1.1774x over previous
//
#include <hip/hip_runtime.h>

#define N_NODES 50000
#define N_EDGES 800000
#define DIN 384
#define DH 128
#define NB 64
#define NEG 0.2f

// ---------------- bf16 helpers (exact bit ops) ----------------
__device__ __forceinline__ float bf2f(unsigned short u) {
    return __uint_as_float((unsigned)u << 16);
}
__device__ __forceinline__ unsigned short f2bf(float x) {  // RNE
    unsigned u = __float_as_uint(x);
    return (unsigned short)((u + 0x7fff + ((u >> 16) & 1)) >> 16);
}
__device__ __forceinline__ float4 bf4_to_f4(const unsigned short* p) {
    ushort4 u = *(const ushort4*)p;
    float4 f;
    f.x = bf2f(u.x); f.y = bf2f(u.y); f.z = bf2f(u.z); f.w = bf2f(u.w);
    return f;
}

// ---------------- edge-weight sum (for self-loop fill value) ----------------
__global__ __launch_bounds__(256) void ewsum_kernel(const float* __restrict__ ew,
                                                    float* __restrict__ out) {
    __shared__ float sred[4];
    const int tid = threadIdx.x;
    float v = 0.0f;
    for (int i = blockIdx.x * 256 + tid; i < N_EDGES; i += gridDim.x * 256)
        v += ew[i];
    #pragma unroll
    for (int o = 32; o; o >>= 1) v += __shfl_down(v, o, 64);
    if ((tid & 63) == 0) sred[tid >> 6] = v;
    __syncthreads();
    if (tid == 0) atomicAdd(out, sred[0] + sred[1] + sred[2] + sred[3]);
}

// ---------------- CSR build: histogram, scan, fill ----------------
__global__ void hist_kernel(const int* __restrict__ dst, int* __restrict__ cnt) {
    int e = blockIdx.x * blockDim.x + threadIdx.x;
    if (e < N_EDGES) atomicAdd(&cnt[dst[e]], 1);
}

__global__ void scan_a(const int* __restrict__ cnt, int* __restrict__ scanned,
                       int* __restrict__ bsums) {
    __shared__ int s[256];
    int tid = threadIdx.x;
    int i = blockIdx.x * 256 + tid;
    int v = (i < N_NODES) ? cnt[i] : 0;
    s[tid] = v; __syncthreads();
    for (int o = 1; o < 256; o <<= 1) {
        int t = (tid >= o) ? s[tid - o] : 0;
        __syncthreads();
        s[tid] += t;
        __syncthreads();
    }
    if (i < N_NODES) scanned[i] = s[tid] - v;  // exclusive
    if (tid == 255) bsums[blockIdx.x] = s[255];
}

__global__ void scan_b(int* __restrict__ bsums, int nb) {
    __shared__ int s[256];
    int tid = threadIdx.x;
    int v = (tid < nb) ? bsums[tid] : 0;
    s[tid] = v; __syncthreads();
    for (int o = 1; o < 256; o <<= 1) {
        int t = (tid >= o) ? s[tid - o] : 0;
        __syncthreads();
        s[tid] += t;
        __syncthreads();
    }
    if (tid < nb) bsums[tid] = s[tid] - v;  // exclusive
}

__global__ void scan_c(const int* __restrict__ scanned, const int* __restrict__ bsums,
                       const int* __restrict__ cnt, int* __restrict__ ptr,
                       int* __restrict__ cursor) {
    int i = blockIdx.x * 256 + threadIdx.x;
    if (i < N_NODES) {
        int p = scanned[i] + bsums[blockIdx.x];
        ptr[i] = p;
        cursor[i] = p;
        if (i == N_NODES - 1) ptr[N_NODES] = p + cnt[i];
    }
}

__global__ void fill_kernel(const int* __restrict__ dst, int* __restrict__ cursor,
                            int* __restrict__ eids) {
    int e = blockIdx.x * blockDim.x + threadIdx.x;
    if (e < N_EDGES) {
        int p = atomicAdd(&cursor[dst[e]], 1);
        eids[p] = e;
    }
}

// ---------------- MFMA bf16 GEMM: C[M,128] = A[M,K] @ W[K,128] (+bias) ----------
// fp32 inputs, cast to bf16 during LDS staging, fp32 MFMA accumulation.
// Block: 256 thr (4 waves), tile BM=64 x BN=128, BK=32.
// Wave w: rows w*16..w*16+15, all 128 cols = 8 MFMA tiles of 16x16x32.
// Verified layouts (m89): A[m=lane&15][k=quad*8+j]; B[n=lane&15][k=quad*8+j];
// C/D col=lane&15, row=quad*4+reg.
template<int K, bool BF16OUT>
__global__ __launch_bounds__(256) void mfma_gemm(const float* __restrict__ A,
                                                 const float* __restrict__ W,
                                                 const float* __restrict__ bias,
                                                 void* __restrict__ Cv, int M)
{
    constexpr int BM = 64, BK = 32;
    constexpr int LS = 40;   // LDS row stride in bf16 (80 B: conflict-spreading pad)
    __shared__ unsigned short As[BM * LS];   // [m][k]
    __shared__ unsigned short Bs[DH * LS];   // [n][k]  (W transposed)
    using short8 = __attribute__((ext_vector_type(8))) short;
    using f32x4  = __attribute__((ext_vector_type(4))) float;

    const int tid = threadIdx.x;
    const int w = tid >> 6, l = tid & 63;
    const int lane16 = l & 15, quad = l >> 4;
    const int m0 = blockIdx.x * BM;

    f32x4 acc[8] = {};

    // A staging: thread -> (row = tid>>2, float4-index = tid&3, +4 on 2nd pass)
    const int ar = tid >> 2, af = tid & 3;
    int arow = m0 + ar; if (arow >= M) arow = M - 1;
    const float* Ap = A + (size_t)arow * K;
    // B staging: thread -> (n = tid&127, k-quad base = tid>>7)
    const int bn = tid & 127, bq = tid >> 7;

    for (int k0 = 0; k0 < K; k0 += BK) {
        __syncthreads();
        #pragma unroll
        for (int i = 0; i < 2; ++i) {
            const int f4 = af + 4 * i;
            float4 v = *(const float4*)(Ap + k0 + f4 * 4);
            ushort4 u = {f2bf(v.x), f2bf(v.y), f2bf(v.z), f2bf(v.w)};
            *(ushort4*)&As[ar * LS + f4 * 4] = u;
        }
        #pragma unroll
        for (int i = 0; i < 4; ++i) {
            const int kq = bq + 2 * i;   // 0..7
            float v0 = W[(size_t)(k0 + kq * 4 + 0) * DH + bn];
            float v1 = W[(size_t)(k0 + kq * 4 + 1) * DH + bn];
            float v2 = W[(size_t)(k0 + kq * 4 + 2) * DH + bn];
            float v3 = W[(size_t)(k0 + kq * 4 + 3) * DH + bn];
            ushort4 u = {f2bf(v0), f2bf(v1), f2bf(v2), f2bf(v3)};
            *(ushort4*)&Bs[bn * LS + kq * 4] = u;
        }
        __syncthreads();
        short8 afrag = *(short8*)&As[(w * 16 + lane16) * LS + quad * 8];
        #pragma unroll
        for (int nt = 0; nt < 8; ++nt) {
            short8 bfrag = *(short8*)&Bs[(nt * 16 + lane16) * LS + quad * 8];
            acc[nt] = __builtin_amdgcn_mfma_f32_16x16x32_bf16(afrag, bfrag, acc[nt], 0, 0, 0);
        }
    }

    const int orow0 = m0 + w * 16 + quad * 4;
    #pragma unroll
    for (int nt = 0; nt < 8; ++nt) {
        const int col = nt * 16 + lane16;
        const float bv = BF16OUT ? 0.0f : bias[col];
        #pragma unroll
        for (int r = 0; r < 4; ++r) {
            const int row = orow0 + r;
            if (row < M) {
                if constexpr (BF16OUT)
                    ((unsigned short*)Cv)[(size_t)row * DH + col] = f2bf(acc[nt][r]);
                else
                    ((float*)Cv)[(size_t)row * DH + col] = acc[nt][r] + bv;
            }
        }
    }
}

// ---------------- per-node attention logits a_src, a_dst (bf16 h) ----------------
__global__ __launch_bounds__(128) void att_kernel(const unsigned short* __restrict__ h,
        const float* __restrict__ a_s, const float* __restrict__ a_d,
        float* __restrict__ asrc, float* __restrict__ adst)
{
    int n = blockIdx.x, t = threadIdx.x;
    float v = bf2f(h[(size_t)n * DH + t]);
    float ps = v * a_s[t], pd = v * a_d[t];
    #pragma unroll
    for (int o = 16; o; o >>= 1) { ps += __shfl_down(ps, o, 32); pd += __shfl_down(pd, o, 32); }
    if ((t & 31) == 0) { int hd = t >> 5; asrc[(size_t)n * 4 + hd] = ps; adst[(size_t)n * 4 + hd] = pd; }
}

// ---------------- msg: one wave per node ----------------
__global__ __launch_bounds__(64) void msg_kernel(
    const unsigned short* __restrict__ h, const float* __restrict__ asrc,
    const float* __restrict__ adst, const float* __restrict__ xres,
    const int* __restrict__ indptr, const int* __restrict__ eids,
    const int* __restrict__ srcarr, const float* __restrict__ ew,
    const float* __restrict__ ewsum,
    const float* __restrict__ Wedge, const float* __restrict__ aedge,
    const float* __restrict__ bias, const float* __restrict__ gamma,
    const float* __restrict__ beta, float* __restrict__ xout)
{
    const int n = blockIdx.x, l = threadIdx.x;
    const int sub = l >> 5, c4 = l & 31, hd = c4 >> 3;
    __shared__ float alL[64][4];
    __shared__ int srcS[64];

    float p0 = Wedge[l] * aedge[l];
    float p1 = Wedge[l + 64] * aedge[l + 64];
    #pragma unroll
    for (int o = 1; o < 32; o <<= 1) { p0 += __shfl_xor(p0, o, 64); p1 += __shfl_xor(p1, o, 64); }
    float cc[4];
    cc[0] = __shfl(p0, 0, 64);  cc[1] = __shfl(p0, 32, 64);
    cc[2] = __shfl(p1, 0, 64);  cc[3] = __shfl(p1, 32, 64);

    const float4 ad4 = *(const float4*)(adst + (size_t)n * 4);
    const float4 as4 = *(const float4*)(asrc + (size_t)n * 4);
    const float adv[4] = {ad4.x, ad4.y, ad4.z, ad4.w};
    const float asv[4] = {as4.x, as4.y, as4.z, as4.w};
    const float ewm = ewsum[0] * (1.0f / N_EDGES);

    float mreg[4], dreg[4];
    #pragma unroll
    for (int k = 0; k < 4; ++k) {
        float a0 = asv[k] + adv[k] + ewm * cc[k];
        a0 = a0 > 0.f ? a0 : NEG * a0;
        mreg[k] = a0; dreg[k] = 1.0f;
    }
    float4 acc = {0.f, 0.f, 0.f, 0.f};
    if (sub == 0) acc = bf4_to_f4(h + (size_t)n * DH + c4 * 4);

    const int st = indptr[n], en = indptr[n + 1];
    for (int base = st; base < en; base += 64) {
        const int cb = min(64, en - base);
        const bool act = l < cb;
        float val[4];
        if (act) {
            const int eid = eids[base + l];
            const int s = srcarr[eid];
            const float wgt = ew[eid];
            srcS[l] = s;
            const float4 a4 = *(const float4*)(asrc + (size_t)s * 4);
            const float av[4] = {a4.x, a4.y, a4.z, a4.w};
            #pragma unroll
            for (int k = 0; k < 4; ++k) {
                float v = av[k] + adv[k] + wgt * cc[k];
                val[k] = v > 0.f ? v : NEG * v;
            }
        } else {
            val[0] = val[1] = val[2] = val[3] = -3.0e38f;
        }
        float mx[4] = {val[0], val[1], val[2], val[3]};
        #pragma unroll
        for (int o = 1; o < 64; o <<= 1) {
            #pragma unroll
            for (int k = 0; k < 4; ++k) mx[k] = fmaxf(mx[k], __shfl_xor(mx[k], o, 64));
        }
        float sc[4], pv[4];
        #pragma unroll
        for (int k = 0; k < 4; ++k) {
            const float nm = fmaxf(mreg[k], mx[k]);
            sc[k] = __expf(mreg[k] - nm);
            pv[k] = act ? __expf(val[k] - nm) : 0.0f;
            mreg[k] = nm;
        }
        float4 pw = {pv[0], pv[1], pv[2], pv[3]};
        *(float4*)alL[l] = pw;
        float sm[4] = {pv[0], pv[1], pv[2], pv[3]};
        #pragma unroll
        for (int o = 1; o < 64; o <<= 1) {
            #pragma unroll
            for (int k = 0; k < 4; ++k) sm[k] += __shfl_xor(sm[k], o, 64);
        }
        #pragma unroll
        for (int k = 0; k < 4; ++k) dreg[k] = dreg[k] * sc[k] + sm[k];
        const float f = sc[hd];
        acc.x *= f; acc.y *= f; acc.z *= f; acc.w *= f;
        __syncthreads();

        const int half = (cb + 1) >> 1;
        for (int j = 0; j < half; ++j) {
            const int e = 2 * j + sub;
            if (e < cb) {
                const int s = srcS[e];
                const float coef = alL[e][hd];
                const float4 hv = bf4_to_f4(h + (size_t)s * DH + c4 * 4);
                acc.x = fmaf(coef, hv.x, acc.x);
                acc.y = fmaf(coef, hv.y, acc.y);
                acc.z = fmaf(coef, hv.z, acc.z);
                acc.w = fmaf(coef, hv.w, acc.w);
            }
        }
        __syncthreads();
    }

    acc.x += __shfl_xor(acc.x, 32, 64);
    acc.y += __shfl_xor(acc.y, 32, 64);
    acc.z += __shfl_xor(acc.z, 32, 64);
    acc.w += __shfl_xor(acc.w, 32, 64);

    const float4 b4 = *(const float4*)(bias + c4 * 4);
    const float inv_d = 1.0f / (dreg[hd] + 1e-16f);
    float4 y;
    y.x = acc.x * inv_d + b4.x;
    y.y = acc.y * inv_d + b4.y;
    y.z = acc.z * inv_d + b4.z;
    y.w = acc.w * inv_d + b4.w;

    float s1 = y.x + y.y + y.z + y.w;
    float s2 = y.x * y.x + y.y * y.y + y.z * y.z + y.w * y.w;
    #pragma unroll
    for (int o = 1; o < 32; o <<= 1) {
        s1 += __shfl_xor(s1, o, 64);
        s2 += __shfl_xor(s2, o, 64);
    }
    const float mu = s1 * (1.0f / DH);
    const float var = s2 * (1.0f / DH) - mu * mu;
    const float rs = rsqrtf(var + 1e-5f);

    if (sub == 0) {
        const float4 g4 = *(const float4*)(gamma + c4 * 4);
        const float4 be4 = *(const float4*)(beta + c4 * 4);
        const float4 r4 = *(const float4*)(xres + (size_t)n * DH + c4 * 4);
        float4 z;
        z.x = (y.x - mu) * rs * g4.x + be4.x;
        z.y = (y.y - mu) * rs * g4.y + be4.y;
        z.z = (y.z - mu) * rs * g4.z + be4.z;
        z.w = (y.w - mu) * rs * g4.w + be4.w;
        z.x = (z.x > 0.f ? z.x : __expf(z.x) - 1.0f) + r4.x;
        z.y = (z.y > 0.f ? z.y : __expf(z.y) - 1.0f) + r4.y;
        z.z = (z.z > 0.f ? z.z : __expf(z.z) - 1.0f) + r4.z;
        z.w = (z.w > 0.f ? z.w : __expf(z.w) - 1.0f) + r4.w;
        *(float4*)(xout + (size_t)n * DH + c4 * 4) = z;
    }
}

// ---------------- global mean pool ----------------
#define PNODES 64
__global__ __launch_bounds__(128) void pool_kernel(const float* __restrict__ x,
        const int* __restrict__ batch, float* __restrict__ pool, int* __restrict__ gcnt)
{
    int t = threadIdx.x;
    int n0 = blockIdx.x * PNODES;
    if (n0 >= N_NODES) return;
    int n1 = min(n0 + PNODES, N_NODES);
    float acc = 0.f; int cn = 0;
    int curb = batch[n0];
    for (int n = n0; n < n1; ++n) {
        int b = batch[n];
        if (b != curb) {
            atomicAdd(&pool[(size_t)curb * DH + t], acc);
            if (t == 0) atomicAdd(&gcnt[curb], cn);
            acc = 0.f; cn = 0; curb = b;
        }
        acc += x[(size_t)n * DH + t];
        ++cn;
    }
    atomicAdd(&pool[(size_t)curb * DH + t], acc);
    if (t == 0) atomicAdd(&gcnt[curb], cn);
}

__global__ void div_kernel(const float* __restrict__ pool, const int* __restrict__ gcnt,
                           float* __restrict__ out)
{
    int i = blockIdx.x * blockDim.x + threadIdx.x;
    if (i < NB * DH) {
        float c = (float)gcnt[i >> 7];
        out[i] = pool[i] / fmaxf(c, 1.0f);
    }
}

// ---------------- launch ----------------
extern "C" void kernel_launch(void* const* d_in, const int* in_sizes, int n_in,
                              void* d_out, int out_size, void* d_ws, size_t ws_size,
                              hipStream_t stream)
{
    const float* nf    = (const float*)d_in[0];
    const int*   esrc  = (const int*)d_in[1];
    const int*   edst  = esrc + N_EDGES;
    const float* ew    = (const float*)d_in[2];
    const int*   batch = (const int*)d_in[3];
    const float* Wp    = (const float*)d_in[4];
    const float* bp    = (const float*)d_in[5];
    const float* Wl[2]  = {(const float*)d_in[6],  (const float*)d_in[14]};
    const float* asl[2] = {(const float*)d_in[7],  (const float*)d_in[15]};
    const float* adl[2] = {(const float*)d_in[8],  (const float*)d_in[16]};
    const float* Wel[2] = {(const float*)d_in[9],  (const float*)d_in[17]};
    const float* ael[2] = {(const float*)d_in[10], (const float*)d_in[18]};
    const float* bl[2]  = {(const float*)d_in[11], (const float*)d_in[19]};
    const float* gl[2]  = {(const float*)d_in[12], (const float*)d_in[20]};
    const float* bel[2] = {(const float*)d_in[13], (const float*)d_in[21]};
    float* outp = (float*)d_out;

    char* w = (char*)d_ws;
    auto alloc = [&](size_t bytes) { char* p = w; w += (bytes + 255) & ~255ull; return p; };
    float* xA     = (float*)alloc((size_t)N_NODES * DH * 4);
    float* xB     = (float*)alloc((size_t)N_NODES * DH * 4);
    unsigned short* hbuf = (unsigned short*)alloc((size_t)N_NODES * DH * 2);
    float* asrc   = (float*)alloc((size_t)N_NODES * 4 * 4);
    float* adst   = (float*)alloc((size_t)N_NODES * 4 * 4);
    float* pool   = (float*)alloc((size_t)NB * DH * 4);
    float* ews    = (float*)alloc(256);
    int* cnt      = (int*)alloc((size_t)N_NODES * 4);
    int* scanned  = (int*)alloc((size_t)N_NODES * 4);
    int* bsums    = (int*)alloc(1024);
    int* ptr      = (int*)alloc((size_t)(N_NODES + 8) * 4);
    int* cursor   = (int*)alloc((size_t)N_NODES * 4);
    int* gcnt     = (int*)alloc(256);
    int* eids     = (int*)alloc((size_t)N_EDGES * 4);

    hipMemsetAsync(ews, 0, 4, stream);
    hipMemsetAsync(cnt, 0, (size_t)N_NODES * 4, stream);
    hipMemsetAsync(pool, 0, (size_t)NB * DH * 4, stream);
    hipMemsetAsync(gcnt, 0, 256, stream);

    const int eb = (N_EDGES + 255) / 256;
    const int sb = (N_NODES + 255) / 256;  // 196

    ewsum_kernel<<<104, 256, 0, stream>>>(ew, ews);
    hist_kernel<<<eb, 256, 0, stream>>>(edst, cnt);
    scan_a<<<sb, 256, 0, stream>>>(cnt, scanned, bsums);
    scan_b<<<1, 256, 0, stream>>>(bsums, sb);
    scan_c<<<sb, 256, 0, stream>>>(scanned, bsums, cnt, ptr, cursor);
    fill_kernel<<<eb, 256, 0, stream>>>(edst, cursor, eids);

    const int gb = (N_NODES + 63) / 64;  // 782
    mfma_gemm<DIN, false><<<gb, 256, 0, stream>>>(nf, Wp, bp, xA, N_NODES);

    const float* xin = xA;
    float* xout = xB;
    for (int l = 0; l < 2; ++l) {
        mfma_gemm<DH, true><<<gb, 256, 0, stream>>>(xin, Wl[l], nullptr, hbuf, N_NODES);
        att_kernel<<<N_NODES, 128, 0, stream>>>(hbuf, asl[l], adl[l], asrc, adst);
        msg_kernel<<<N_NODES, 64, 0, stream>>>(hbuf, asrc, adst, xin, ptr, eids, esrc, ew, ews,
                                               Wel[l], ael[l], bl[l], gl[l], bel[l], xout);
        float* tmp = (float*)xin; xin = xout; xout = tmp;
    }

    pool_kernel<<<(N_NODES + PNODES - 1) / PNODES, 128, 0, stream>>>(xin, batch, pool, gcnt);
    div_kernel<<<(NB * DH + 255) / 256, 256, 0, stream>>>(pool, gcnt, outp);
}

// Round 6
// 471.930 us; speedup vs baseline: 1.9577x; 1.0428x over previous
//
#include <hip/hip_runtime.h>

#define N_NODES 50000
#define N_EDGES 800000
#define DIN 384
#define DH 128
#define NB 64
#define NEG 0.2f

// ---------------- bf16 helpers (exact bit ops) ----------------
__device__ __forceinline__ float bf2f(unsigned short u) {
    return __uint_as_float((unsigned)u << 16);
}
__device__ __forceinline__ unsigned short f2bf(float x) {  // RNE
    unsigned u = __float_as_uint(x);
    return (unsigned short)((u + 0x7fff + ((u >> 16) & 1)) >> 16);
}
__device__ __forceinline__ float4 bf4_to_f4(const unsigned short* p) {
    ushort4 u = *(const ushort4*)p;
    float4 f;
    f.x = bf2f(u.x); f.y = bf2f(u.y); f.z = bf2f(u.z); f.w = bf2f(u.w);
    return f;
}

// ---------------- edge-weight sum (for self-loop fill value) ----------------
__global__ __launch_bounds__(256) void ewsum_kernel(const float* __restrict__ ew,
                                                    float* __restrict__ out) {
    __shared__ float sred[4];
    const int tid = threadIdx.x;
    float v = 0.0f;
    for (int i = blockIdx.x * 256 + tid; i < N_EDGES; i += gridDim.x * 256)
        v += ew[i];
    #pragma unroll
    for (int o = 32; o; o >>= 1) v += __shfl_down(v, o, 64);
    if ((tid & 63) == 0) sred[tid >> 6] = v;
    __syncthreads();
    if (tid == 0) atomicAdd(out, sred[0] + sred[1] + sred[2] + sred[3]);
}

// ---------------- CSR build: histogram, scan, fill ----------------
__global__ void hist_kernel(const int* __restrict__ dst, int* __restrict__ cnt) {
    int e = blockIdx.x * blockDim.x + threadIdx.x;
    if (e < N_EDGES) atomicAdd(&cnt[dst[e]], 1);
}

__global__ void scan_a(const int* __restrict__ cnt, int* __restrict__ scanned,
                       int* __restrict__ bsums) {
    __shared__ int s[256];
    int tid = threadIdx.x;
    int i = blockIdx.x * 256 + tid;
    int v = (i < N_NODES) ? cnt[i] : 0;
    s[tid] = v; __syncthreads();
    for (int o = 1; o < 256; o <<= 1) {
        int t = (tid >= o) ? s[tid - o] : 0;
        __syncthreads();
        s[tid] += t;
        __syncthreads();
    }
    if (i < N_NODES) scanned[i] = s[tid] - v;  // exclusive
    if (tid == 255) bsums[blockIdx.x] = s[255];
}

__global__ void scan_b(int* __restrict__ bsums, int nb) {
    __shared__ int s[256];
    int tid = threadIdx.x;
    int v = (tid < nb) ? bsums[tid] : 0;
    s[tid] = v; __syncthreads();
    for (int o = 1; o < 256; o <<= 1) {
        int t = (tid >= o) ? s[tid - o] : 0;
        __syncthreads();
        s[tid] += t;
        __syncthreads();
    }
    if (tid < nb) bsums[tid] = s[tid] - v;  // exclusive
}

__global__ void scan_c(const int* __restrict__ scanned, const int* __restrict__ bsums,
                       const int* __restrict__ cnt, int* __restrict__ ptr,
                       int* __restrict__ cursor) {
    int i = blockIdx.x * 256 + threadIdx.x;
    if (i < N_NODES) {
        int p = scanned[i] + bsums[blockIdx.x];
        ptr[i] = p;
        cursor[i] = p;
        if (i == N_NODES - 1) ptr[N_NODES] = p + cnt[i];
    }
}

__global__ void fill_kernel(const int* __restrict__ dst, int* __restrict__ cursor,
                            int* __restrict__ eids) {
    int e = blockIdx.x * blockDim.x + threadIdx.x;
    if (e < N_EDGES) {
        int p = atomicAdd(&cursor[dst[e]], 1);
        eids[p] = e;
    }
}

// ---------------- MFMA bf16 GEMM: C[M,128] = A[M,K] @ W[K,128] (+bias) ----------
template<int K, bool BF16OUT>
__global__ __launch_bounds__(256) void mfma_gemm(const float* __restrict__ A,
                                                 const float* __restrict__ W,
                                                 const float* __restrict__ bias,
                                                 void* __restrict__ Cv, int M)
{
    constexpr int BM = 64, BK = 32;
    constexpr int LS = 40;   // LDS row stride in bf16 (80 B: conflict-spreading pad)
    __shared__ unsigned short As[BM * LS];   // [m][k]
    __shared__ unsigned short Bs[DH * LS];   // [n][k]  (W transposed)
    using short8 = __attribute__((ext_vector_type(8))) short;
    using f32x4  = __attribute__((ext_vector_type(4))) float;

    const int tid = threadIdx.x;
    const int w = tid >> 6, l = tid & 63;
    const int lane16 = l & 15, quad = l >> 4;
    const int m0 = blockIdx.x * BM;

    f32x4 acc[8] = {};

    const int ar = tid >> 2, af = tid & 3;
    int arow = m0 + ar; if (arow >= M) arow = M - 1;
    const float* Ap = A + (size_t)arow * K;
    const int bn = tid & 127, bq = tid >> 7;

    for (int k0 = 0; k0 < K; k0 += BK) {
        __syncthreads();
        #pragma unroll
        for (int i = 0; i < 2; ++i) {
            const int f4 = af + 4 * i;
            float4 v = *(const float4*)(Ap + k0 + f4 * 4);
            ushort4 u = {f2bf(v.x), f2bf(v.y), f2bf(v.z), f2bf(v.w)};
            *(ushort4*)&As[ar * LS + f4 * 4] = u;
        }
        #pragma unroll
        for (int i = 0; i < 4; ++i) {
            const int kq = bq + 2 * i;   // 0..7
            float v0 = W[(size_t)(k0 + kq * 4 + 0) * DH + bn];
            float v1 = W[(size_t)(k0 + kq * 4 + 1) * DH + bn];
            float v2 = W[(size_t)(k0 + kq * 4 + 2) * DH + bn];
            float v3 = W[(size_t)(k0 + kq * 4 + 3) * DH + bn];
            ushort4 u = {f2bf(v0), f2bf(v1), f2bf(v2), f2bf(v3)};
            *(ushort4*)&Bs[bn * LS + kq * 4] = u;
        }
        __syncthreads();
        short8 afrag = *(short8*)&As[(w * 16 + lane16) * LS + quad * 8];
        #pragma unroll
        for (int nt = 0; nt < 8; ++nt) {
            short8 bfrag = *(short8*)&Bs[(nt * 16 + lane16) * LS + quad * 8];
            acc[nt] = __builtin_amdgcn_mfma_f32_16x16x32_bf16(afrag, bfrag, acc[nt], 0, 0, 0);
        }
    }

    const int orow0 = m0 + w * 16 + quad * 4;
    #pragma unroll
    for (int nt = 0; nt < 8; ++nt) {
        const int col = nt * 16 + lane16;
        const float bv = BF16OUT ? 0.0f : bias[col];
        #pragma unroll
        for (int r = 0; r < 4; ++r) {
            const int row = orow0 + r;
            if (row < M) {
                if constexpr (BF16OUT)
                    ((unsigned short*)Cv)[(size_t)row * DH + col] = f2bf(acc[nt][r]);
                else
                    ((float*)Cv)[(size_t)row * DH + col] = acc[nt][r] + bv;
            }
        }
    }
}

// ---------------- per-node attention logits (8 nodes / 256-thr block) ----------
__global__ __launch_bounds__(256) void att_kernel(const unsigned short* __restrict__ h,
        const float* __restrict__ a_s, const float* __restrict__ a_d,
        float* __restrict__ asrc, float* __restrict__ adst)
{
    const int tid = threadIdx.x;
    const int g = tid >> 5, lane32 = tid & 31;
    const int n = blockIdx.x * 8 + g;
    if (n >= N_NODES) return;
    const float4 v = bf4_to_f4(h + (size_t)n * DH + lane32 * 4);
    const float4 s4 = *(const float4*)(a_s + lane32 * 4);
    const float4 d4 = *(const float4*)(a_d + lane32 * 4);
    float ps = v.x * s4.x + v.y * s4.y + v.z * s4.z + v.w * s4.w;
    float pd = v.x * d4.x + v.y * d4.y + v.z * d4.z + v.w * d4.w;
    // per-head reduction: 8 lanes x 4 ch = one head
    #pragma unroll
    for (int o = 1; o < 8; o <<= 1) {
        ps += __shfl_xor(ps, o, 64);
        pd += __shfl_xor(pd, o, 64);
    }
    if ((lane32 & 7) == 0) {
        const int hd = lane32 >> 3;
        asrc[(size_t)n * 4 + hd] = ps;
        adst[(size_t)n * 4 + hd] = pd;
    }
}

// ---------------- msg: one wave per node, no-max softmax ----------------
// All logits |alpha| << 1 (0.02-scale weights), so exp() without max-subtraction
// is exact softmax (shift-invariant) — removes all per-chunk butterflies.
__global__ __launch_bounds__(64) void msg_kernel(
    const unsigned short* __restrict__ h, const float* __restrict__ asrc,
    const float* __restrict__ adst, const float* __restrict__ xres,
    const int* __restrict__ indptr, const int* __restrict__ eids,
    const int* __restrict__ srcarr, const float* __restrict__ ew,
    const float* __restrict__ ewsum,
    const float* __restrict__ Wedge, const float* __restrict__ aedge,
    const float* __restrict__ bias, const float* __restrict__ gamma,
    const float* __restrict__ beta, float* __restrict__ xout)
{
    const int n = blockIdx.x, l = threadIdx.x;
    const int sub = l >> 5, c4 = l & 31, hd = c4 >> 3;
    __shared__ float alL[64][4];
    __shared__ int srcS[64];

    // c[k] = dot(We_k, ae_k)
    float p0 = Wedge[l] * aedge[l];
    float p1 = Wedge[l + 64] * aedge[l + 64];
    #pragma unroll
    for (int o = 1; o < 32; o <<= 1) { p0 += __shfl_xor(p0, o, 64); p1 += __shfl_xor(p1, o, 64); }
    float cc[4];
    cc[0] = __shfl(p0, 0, 64);  cc[1] = __shfl(p0, 32, 64);
    cc[2] = __shfl(p1, 0, 64);  cc[3] = __shfl(p1, 32, 64);

    const float4 ad4 = *(const float4*)(adst + (size_t)n * 4);
    const float4 as4 = *(const float4*)(asrc + (size_t)n * 4);
    const float adv[4] = {ad4.x, ad4.y, ad4.z, ad4.w};
    const float asv[4] = {as4.x, as4.y, as4.z, as4.w};
    const float ewm = ewsum[0] * (1.0f / N_EDGES);

    // self-loop contribution (no max-shift needed)
    float pv0[4];
    #pragma unroll
    for (int k = 0; k < 4; ++k) {
        float a0 = asv[k] + adv[k] + ewm * cc[k];
        a0 = a0 > 0.f ? a0 : NEG * a0;
        pv0[k] = __expf(a0);
    }
    float dsum[4] = {0.f, 0.f, 0.f, 0.f};  // per-lane partial denominators
    float4 acc = {0.f, 0.f, 0.f, 0.f};
    if (sub == 0) {
        const float4 h4 = bf4_to_f4(h + (size_t)n * DH + c4 * 4);
        const float f = pv0[hd];
        acc.x = f * h4.x; acc.y = f * h4.y; acc.z = f * h4.z; acc.w = f * h4.w;
    }

    const int st = indptr[n], en = indptr[n + 1];
    for (int base = st; base < en; base += 64) {
        const int cb = min(64, en - base);
        if (l < cb) {
            const int eid = eids[base + l];
            const int s = srcarr[eid];
            const float wgt = ew[eid];
            srcS[l] = s;
            const float4 a4 = *(const float4*)(asrc + (size_t)s * 4);
            const float av[4] = {a4.x, a4.y, a4.z, a4.w};
            float pw[4];
            #pragma unroll
            for (int k = 0; k < 4; ++k) {
                float v = av[k] + adv[k] + wgt * cc[k];
                v = v > 0.f ? v : NEG * v;
                pw[k] = __expf(v);
                dsum[k] += pw[k];
            }
            float4 p4 = {pw[0], pw[1], pw[2], pw[3]};
            *(float4*)alL[l] = p4;
        }
        __syncthreads();
        // gather, 4 edges in flight per lane (edges e = sub, sub+2, ...)
        int e = sub;
        for (; e + 6 < cb; e += 8) {
            const int s0 = srcS[e],     s1 = srcS[e + 2];
            const int s2 = srcS[e + 4], s3 = srcS[e + 6];
            const float c0 = alL[e][hd],     c1 = alL[e + 2][hd];
            const float c2 = alL[e + 4][hd], c3 = alL[e + 6][hd];
            const float4 h0 = bf4_to_f4(h + (size_t)s0 * DH + c4 * 4);
            const float4 h1 = bf4_to_f4(h + (size_t)s1 * DH + c4 * 4);
            const float4 h2 = bf4_to_f4(h + (size_t)s2 * DH + c4 * 4);
            const float4 h3 = bf4_to_f4(h + (size_t)s3 * DH + c4 * 4);
            acc.x = fmaf(c0, h0.x, fmaf(c1, h1.x, fmaf(c2, h2.x, fmaf(c3, h3.x, acc.x))));
            acc.y = fmaf(c0, h0.y, fmaf(c1, h1.y, fmaf(c2, h2.y, fmaf(c3, h3.y, acc.y))));
            acc.z = fmaf(c0, h0.z, fmaf(c1, h1.z, fmaf(c2, h2.z, fmaf(c3, h3.z, acc.z))));
            acc.w = fmaf(c0, h0.w, fmaf(c1, h1.w, fmaf(c2, h2.w, fmaf(c3, h3.w, acc.w))));
        }
        for (; e < cb; e += 2) {
            const int s = srcS[e];
            const float coef = alL[e][hd];
            const float4 hv = bf4_to_f4(h + (size_t)s * DH + c4 * 4);
            acc.x = fmaf(coef, hv.x, acc.x);
            acc.y = fmaf(coef, hv.y, acc.y);
            acc.z = fmaf(coef, hv.z, acc.z);
            acc.w = fmaf(coef, hv.w, acc.w);
        }
        __syncthreads();
    }

    // total denominator: reduce per-lane partials over all 64 lanes, add self
    #pragma unroll
    for (int o = 1; o < 64; o <<= 1) {
        #pragma unroll
        for (int k = 0; k < 4; ++k) dsum[k] += __shfl_xor(dsum[k], o, 64);
    }
    // combine edge-parity halves of acc
    acc.x += __shfl_xor(acc.x, 32, 64);
    acc.y += __shfl_xor(acc.y, 32, 64);
    acc.z += __shfl_xor(acc.z, 32, 64);
    acc.w += __shfl_xor(acc.w, 32, 64);

    const float4 b4 = *(const float4*)(bias + c4 * 4);
    const float inv_d = 1.0f / (dsum[hd] + pv0[hd] + 1e-16f);
    float4 y;
    y.x = acc.x * inv_d + b4.x;
    y.y = acc.y * inv_d + b4.y;
    y.z = acc.z * inv_d + b4.z;
    y.w = acc.w * inv_d + b4.w;

    float s1 = y.x + y.y + y.z + y.w;
    float s2 = y.x * y.x + y.y * y.y + y.z * y.z + y.w * y.w;
    #pragma unroll
    for (int o = 1; o < 32; o <<= 1) {
        s1 += __shfl_xor(s1, o, 64);
        s2 += __shfl_xor(s2, o, 64);
    }
    const float mu = s1 * (1.0f / DH);
    const float var = s2 * (1.0f / DH) - mu * mu;
    const float rs = rsqrtf(var + 1e-5f);

    if (sub == 0) {
        const float4 g4 = *(const float4*)(gamma + c4 * 4);
        const float4 be4 = *(const float4*)(beta + c4 * 4);
        const float4 r4 = *(const float4*)(xres + (size_t)n * DH + c4 * 4);
        float4 z;
        z.x = (y.x - mu) * rs * g4.x + be4.x;
        z.y = (y.y - mu) * rs * g4.y + be4.y;
        z.z = (y.z - mu) * rs * g4.z + be4.z;
        z.w = (y.w - mu) * rs * g4.w + be4.w;
        z.x = (z.x > 0.f ? z.x : __expf(z.x) - 1.0f) + r4.x;
        z.y = (z.y > 0.f ? z.y : __expf(z.y) - 1.0f) + r4.y;
        z.z = (z.z > 0.f ? z.z : __expf(z.z) - 1.0f) + r4.z;
        z.w = (z.w > 0.f ? z.w : __expf(z.w) - 1.0f) + r4.w;
        *(float4*)(xout + (size_t)n * DH + c4 * 4) = z;
    }
}

// ---------------- global mean pool ----------------
#define PNODES 64
__global__ __launch_bounds__(128) void pool_kernel(const float* __restrict__ x,
        const int* __restrict__ batch, float* __restrict__ pool, int* __restrict__ gcnt)
{
    int t = threadIdx.x;
    int n0 = blockIdx.x * PNODES;
    if (n0 >= N_NODES) return;
    int n1 = min(n0 + PNODES, N_NODES);
    float acc = 0.f; int cn = 0;
    int curb = batch[n0];
    for (int n = n0; n < n1; ++n) {
        int b = batch[n];
        if (b != curb) {
            atomicAdd(&pool[(size_t)curb * DH + t], acc);
            if (t == 0) atomicAdd(&gcnt[curb], cn);
            acc = 0.f; cn = 0; curb = b;
        }
        acc += x[(size_t)n * DH + t];
        ++cn;
    }
    atomicAdd(&pool[(size_t)curb * DH + t], acc);
    if (t == 0) atomicAdd(&gcnt[curb], cn);
}

__global__ void div_kernel(const float* __restrict__ pool, const int* __restrict__ gcnt,
                           float* __restrict__ out)
{
    int i = blockIdx.x * blockDim.x + threadIdx.x;
    if (i < NB * DH) {
        float c = (float)gcnt[i >> 7];
        out[i] = pool[i] / fmaxf(c, 1.0f);
    }
}

// ---------------- launch ----------------
extern "C" void kernel_launch(void* const* d_in, const int* in_sizes, int n_in,
                              void* d_out, int out_size, void* d_ws, size_t ws_size,
                              hipStream_t stream)
{
    const float* nf    = (const float*)d_in[0];
    const int*   esrc  = (const int*)d_in[1];
    const int*   edst  = esrc + N_EDGES;
    const float* ew    = (const float*)d_in[2];
    const int*   batch = (const int*)d_in[3];
    const float* Wp    = (const float*)d_in[4];
    const float* bp    = (const float*)d_in[5];
    const float* Wl[2]  = {(const float*)d_in[6],  (const float*)d_in[14]};
    const float* asl[2] = {(const float*)d_in[7],  (const float*)d_in[15]};
    const float* adl[2] = {(const float*)d_in[8],  (const float*)d_in[16]};
    const float* Wel[2] = {(const float*)d_in[9],  (const float*)d_in[17]};
    const float* ael[2] = {(const float*)d_in[10], (const float*)d_in[18]};
    const float* bl[2]  = {(const float*)d_in[11], (const float*)d_in[19]};
    const float* gl[2]  = {(const float*)d_in[12], (const float*)d_in[20]};
    const float* bel[2] = {(const float*)d_in[13], (const float*)d_in[21]};
    float* outp = (float*)d_out;

    char* w = (char*)d_ws;
    auto alloc = [&](size_t bytes) { char* p = w; w += (bytes + 255) & ~255ull; return p; };
    float* xA     = (float*)alloc((size_t)N_NODES * DH * 4);
    float* xB     = (float*)alloc((size_t)N_NODES * DH * 4);
    unsigned short* hbuf = (unsigned short*)alloc((size_t)N_NODES * DH * 2);
    float* asrc   = (float*)alloc((size_t)N_NODES * 4 * 4);
    float* adst   = (float*)alloc((size_t)N_NODES * 4 * 4);
    // contiguous zero-init group: pool | gcnt | ews | cnt  (one memset)
    float* pool   = (float*)alloc((size_t)NB * DH * 4);     // 32768 B
    int* gcnt     = (int*)alloc(256);
    float* ews    = (float*)alloc(256);
    int* cnt      = (int*)alloc((size_t)N_NODES * 4);
    int* scanned  = (int*)alloc((size_t)N_NODES * 4);
    int* bsums    = (int*)alloc(1024);
    int* ptr      = (int*)alloc((size_t)(N_NODES + 8) * 4);
    int* cursor   = (int*)alloc((size_t)N_NODES * 4);
    int* eids     = (int*)alloc((size_t)N_EDGES * 4);

    hipMemsetAsync(pool, 0, (size_t)NB * DH * 4 + 256 + 256 + (size_t)N_NODES * 4, stream);

    const int eb = (N_EDGES + 255) / 256;
    const int sb = (N_NODES + 255) / 256;  // 196

    ewsum_kernel<<<104, 256, 0, stream>>>(ew, ews);
    hist_kernel<<<eb, 256, 0, stream>>>(edst, cnt);
    scan_a<<<sb, 256, 0, stream>>>(cnt, scanned, bsums);
    scan_b<<<1, 256, 0, stream>>>(bsums, sb);
    scan_c<<<sb, 256, 0, stream>>>(scanned, bsums, cnt, ptr, cursor);
    fill_kernel<<<eb, 256, 0, stream>>>(edst, cursor, eids);

    const int gb = (N_NODES + 63) / 64;  // 782
    mfma_gemm<DIN, false><<<gb, 256, 0, stream>>>(nf, Wp, bp, xA, N_NODES);

    const float* xin = xA;
    float* xout = xB;
    for (int l = 0; l < 2; ++l) {
        mfma_gemm<DH, true><<<gb, 256, 0, stream>>>(xin, Wl[l], nullptr, hbuf, N_NODES);
        att_kernel<<<(N_NODES + 7) / 8, 256, 0, stream>>>(hbuf, asl[l], adl[l], asrc, adst);
        msg_kernel<<<N_NODES, 64, 0, stream>>>(hbuf, asrc, adst, xin, ptr, eids, esrc, ew, ews,
                                               Wel[l], ael[l], bl[l], gl[l], bel[l], xout);
        float* tmp = (float*)xin; xin = xout; xout = tmp;
    }

    pool_kernel<<<(N_NODES + PNODES - 1) / PNODES, 128, 0, stream>>>(xin, batch, pool, gcnt);
    div_kernel<<<(NB * DH + 255) / 256, 256, 0, stream>>>(pool, gcnt, outp);
}

// Round 7
// 449.315 us; speedup vs baseline: 2.0563x; 1.0503x over previous
//
#include <hip/hip_runtime.h>

#define N_NODES 50000
#define N_EDGES 800000
#define DIN 384
#define DH 128
#define NB 64
#define NEG 0.2f

// ---------------- bf16 helpers (exact bit ops) ----------------
__device__ __forceinline__ float bf2f(unsigned short u) {
    return __uint_as_float((unsigned)u << 16);
}
__device__ __forceinline__ unsigned short f2bf(float x) {  // RNE
    unsigned u = __float_as_uint(x);
    return (unsigned short)((u + 0x7fff + ((u >> 16) & 1)) >> 16);
}
__device__ __forceinline__ float4 bf4_to_f4(const unsigned short* p) {
    ushort4 u = *(const ushort4*)p;
    float4 f;
    f.x = bf2f(u.x); f.y = bf2f(u.y); f.z = bf2f(u.z); f.w = bf2f(u.w);
    return f;
}
using us8 = __attribute__((ext_vector_type(8))) unsigned short;

// ---------------- edge-weight sum (for self-loop fill value) ----------------
__global__ __launch_bounds__(256) void ewsum_kernel(const float* __restrict__ ew,
                                                    float* __restrict__ out) {
    __shared__ float sred[4];
    const int tid = threadIdx.x;
    float v = 0.0f;
    for (int i = blockIdx.x * 256 + tid; i < N_EDGES; i += gridDim.x * 256)
        v += ew[i];
    #pragma unroll
    for (int o = 32; o; o >>= 1) v += __shfl_down(v, o, 64);
    if ((tid & 63) == 0) sred[tid >> 6] = v;
    __syncthreads();
    if (tid == 0) atomicAdd(out, sred[0] + sred[1] + sred[2] + sred[3]);
}

// ---------------- CSR build: histogram, scan, fill ----------------
__global__ void hist_kernel(const int* __restrict__ dst, int* __restrict__ cnt) {
    int e = blockIdx.x * blockDim.x + threadIdx.x;
    if (e < N_EDGES) atomicAdd(&cnt[dst[e]], 1);
}

__global__ void scan_a(const int* __restrict__ cnt, int* __restrict__ scanned,
                       int* __restrict__ bsums) {
    __shared__ int s[256];
    int tid = threadIdx.x;
    int i = blockIdx.x * 256 + tid;
    int v = (i < N_NODES) ? cnt[i] : 0;
    s[tid] = v; __syncthreads();
    for (int o = 1; o < 256; o <<= 1) {
        int t = (tid >= o) ? s[tid - o] : 0;
        __syncthreads();
        s[tid] += t;
        __syncthreads();
    }
    if (i < N_NODES) scanned[i] = s[tid] - v;  // exclusive
    if (tid == 255) bsums[blockIdx.x] = s[255];
}

__global__ void scan_b(int* __restrict__ bsums, int nb) {
    __shared__ int s[256];
    int tid = threadIdx.x;
    int v = (tid < nb) ? bsums[tid] : 0;
    s[tid] = v; __syncthreads();
    for (int o = 1; o < 256; o <<= 1) {
        int t = (tid >= o) ? s[tid - o] : 0;
        __syncthreads();
        s[tid] += t;
        __syncthreads();
    }
    if (tid < nb) bsums[tid] = s[tid] - v;  // exclusive
}

__global__ void scan_c(const int* __restrict__ scanned, const int* __restrict__ bsums,
                       const int* __restrict__ cnt, int* __restrict__ ptr,
                       int* __restrict__ cursor) {
    int i = blockIdx.x * 256 + threadIdx.x;
    if (i < N_NODES) {
        int p = scanned[i] + bsums[blockIdx.x];
        ptr[i] = p;
        cursor[i] = p;
        if (i == N_NODES - 1) ptr[N_NODES] = p + cnt[i];
    }
}

// fill: write src & weight directly into dst-sorted order — msg then reads them
// sequentially (removes the eids->srcarr dependent random hop from msg's chain).
__global__ void fill_kernel(const int* __restrict__ src, const int* __restrict__ dst,
                            const float* __restrict__ ew, int* __restrict__ cursor,
                            int* __restrict__ srcQ, float* __restrict__ ewQ) {
    int e = blockIdx.x * blockDim.x + threadIdx.x;
    if (e < N_EDGES) {
        int p = atomicAdd(&cursor[dst[e]], 1);
        srcQ[p] = src[e];
        ewQ[p] = ew[e];
    }
}

// ---------------- MFMA bf16 GEMM: C[M,128] = A[M,K] @ W[K,128] (+bias) ----------
template<int K, bool BF16OUT>
__global__ __launch_bounds__(256) void mfma_gemm(const float* __restrict__ A,
                                                 const float* __restrict__ W,
                                                 const float* __restrict__ bias,
                                                 void* __restrict__ Cv, int M)
{
    constexpr int BM = 64, BK = 32;
    constexpr int LS = 40;   // LDS row stride in bf16 (80 B: conflict-spreading pad)
    __shared__ unsigned short As[BM * LS];   // [m][k]
    __shared__ unsigned short Bs[DH * LS];   // [n][k]  (W transposed)
    using short8 = __attribute__((ext_vector_type(8))) short;
    using f32x4  = __attribute__((ext_vector_type(4))) float;

    const int tid = threadIdx.x;
    const int w = tid >> 6, l = tid & 63;
    const int lane16 = l & 15, quad = l >> 4;
    const int m0 = blockIdx.x * BM;

    f32x4 acc[8] = {};

    const int ar = tid >> 2, af = tid & 3;
    int arow = m0 + ar; if (arow >= M) arow = M - 1;
    const float* Ap = A + (size_t)arow * K;
    const int bn = tid & 127, bq = tid >> 7;

    for (int k0 = 0; k0 < K; k0 += BK) {
        __syncthreads();
        #pragma unroll
        for (int i = 0; i < 2; ++i) {
            const int f4 = af + 4 * i;
            float4 v = *(const float4*)(Ap + k0 + f4 * 4);
            ushort4 u = {f2bf(v.x), f2bf(v.y), f2bf(v.z), f2bf(v.w)};
            *(ushort4*)&As[ar * LS + f4 * 4] = u;
        }
        #pragma unroll
        for (int i = 0; i < 4; ++i) {
            const int kq = bq + 2 * i;   // 0..7
            float v0 = W[(size_t)(k0 + kq * 4 + 0) * DH + bn];
            float v1 = W[(size_t)(k0 + kq * 4 + 1) * DH + bn];
            float v2 = W[(size_t)(k0 + kq * 4 + 2) * DH + bn];
            float v3 = W[(size_t)(k0 + kq * 4 + 3) * DH + bn];
            ushort4 u = {f2bf(v0), f2bf(v1), f2bf(v2), f2bf(v3)};
            *(ushort4*)&Bs[bn * LS + kq * 4] = u;
        }
        __syncthreads();
        short8 afrag = *(short8*)&As[(w * 16 + lane16) * LS + quad * 8];
        #pragma unroll
        for (int nt = 0; nt < 8; ++nt) {
            short8 bfrag = *(short8*)&Bs[(nt * 16 + lane16) * LS + quad * 8];
            acc[nt] = __builtin_amdgcn_mfma_f32_16x16x32_bf16(afrag, bfrag, acc[nt], 0, 0, 0);
        }
    }

    const int orow0 = m0 + w * 16 + quad * 4;
    #pragma unroll
    for (int nt = 0; nt < 8; ++nt) {
        const int col = nt * 16 + lane16;
        const float bv = BF16OUT ? 0.0f : bias[col];
        #pragma unroll
        for (int r = 0; r < 4; ++r) {
            const int row = orow0 + r;
            if (row < M) {
                if constexpr (BF16OUT)
                    ((unsigned short*)Cv)[(size_t)row * DH + col] = f2bf(acc[nt][r]);
                else
                    ((float*)Cv)[(size_t)row * DH + col] = acc[nt][r] + bv;
            }
        }
    }
}

// ---------------- per-node attention logits (8 nodes / 256-thr block) ----------
__global__ __launch_bounds__(256) void att_kernel(const unsigned short* __restrict__ h,
        const float* __restrict__ a_s, const float* __restrict__ a_d,
        float* __restrict__ asrc, float* __restrict__ adst)
{
    const int tid = threadIdx.x;
    const int g = tid >> 5, lane32 = tid & 31;
    const int n = blockIdx.x * 8 + g;
    if (n >= N_NODES) return;
    const float4 v = bf4_to_f4(h + (size_t)n * DH + lane32 * 4);
    const float4 s4 = *(const float4*)(a_s + lane32 * 4);
    const float4 d4 = *(const float4*)(a_d + lane32 * 4);
    float ps = v.x * s4.x + v.y * s4.y + v.z * s4.z + v.w * s4.w;
    float pd = v.x * d4.x + v.y * d4.y + v.z * d4.z + v.w * d4.w;
    #pragma unroll
    for (int o = 1; o < 8; o <<= 1) {
        ps += __shfl_xor(ps, o, 64);
        pd += __shfl_xor(pd, o, 64);
    }
    if ((lane32 & 7) == 0) {
        const int hd = lane32 >> 3;
        asrc[(size_t)n * 4 + hd] = ps;
        adst[(size_t)n * 4 + hd] = pd;
    }
}

// ---------------- msg: one wave per node, 16 B/lane gather ----------------
// Lane l: sub2 = l>>4 (edge parity 0..3), c8 = l&15 (channels c8*8..c8*8+7).
// 16 lanes x 16 B cover one 256 B h-row; 4 rows in flight per step.
__global__ __launch_bounds__(64) void msg_kernel(
    const unsigned short* __restrict__ h, const float* __restrict__ asrc,
    const float* __restrict__ adst, const float* __restrict__ xres,
    const int* __restrict__ indptr, const int* __restrict__ srcQ,
    const float* __restrict__ ewQ, const float* __restrict__ ewsum,
    const float* __restrict__ Wedge, const float* __restrict__ aedge,
    const float* __restrict__ bias, const float* __restrict__ gamma,
    const float* __restrict__ beta, float* __restrict__ xout)
{
    const int n = blockIdx.x, l = threadIdx.x;
    const int sub2 = l >> 4, c8 = l & 15, hd8 = c8 >> 2;
    __shared__ float alL[64][4];
    __shared__ int srcS[64];

    // c[k] = dot(We_k, ae_k)
    float p0 = Wedge[l] * aedge[l];
    float p1 = Wedge[l + 64] * aedge[l + 64];
    #pragma unroll
    for (int o = 1; o < 32; o <<= 1) { p0 += __shfl_xor(p0, o, 64); p1 += __shfl_xor(p1, o, 64); }
    float cc[4];
    cc[0] = __shfl(p0, 0, 64);  cc[1] = __shfl(p0, 32, 64);
    cc[2] = __shfl(p1, 0, 64);  cc[3] = __shfl(p1, 32, 64);

    const float4 ad4 = *(const float4*)(adst + (size_t)n * 4);
    const float4 as4 = *(const float4*)(asrc + (size_t)n * 4);
    const float adv[4] = {ad4.x, ad4.y, ad4.z, ad4.w};
    const float ewm = ewsum[0] * (1.0f / N_EDGES);

    // self-loop contribution (no max-shift: |alpha| << 1, softmax shift-invariant)
    float pv0[4];
    {
        const float asv[4] = {as4.x, as4.y, as4.z, as4.w};
        #pragma unroll
        for (int k = 0; k < 4; ++k) {
            float a0 = asv[k] + adv[k] + ewm * cc[k];
            a0 = a0 > 0.f ? a0 : NEG * a0;
            pv0[k] = __expf(a0);
        }
    }
    float dsum[4] = {0.f, 0.f, 0.f, 0.f};
    float acc8[8] = {};
    const unsigned short* hb = h + c8 * 8;
    if (sub2 == 0) {
        us8 u = *(const us8*)(hb + (size_t)n * DH);
        const float f = pv0[hd8];
        #pragma unroll
        for (int i = 0; i < 8; ++i) acc8[i] = f * bf2f(u[i]);
    }

    const int st = indptr[n], en = indptr[n + 1];
    for (int base = st; base < en; base += 64) {
        const int cb = min(64, en - base);
        if (l < cb) {
            const int s = srcQ[base + l];
            const float wgt = ewQ[base + l];
            srcS[l] = s;
            const float4 a4 = *(const float4*)(asrc + (size_t)s * 4);
            const float av[4] = {a4.x, a4.y, a4.z, a4.w};
            float pw[4];
            #pragma unroll
            for (int k = 0; k < 4; ++k) {
                float v = av[k] + adv[k] + wgt * cc[k];
                v = v > 0.f ? v : NEG * v;
                pw[k] = __expf(v);
                dsum[k] += pw[k];
            }
            float4 p4 = {pw[0], pw[1], pw[2], pw[3]};
            *(float4*)alL[l] = p4;
        }
        __syncthreads();
        int e = sub2;
        for (; e + 12 < cb; e += 16) {
            const int s0 = srcS[e],     s1 = srcS[e + 4];
            const int s2 = srcS[e + 8], s3 = srcS[e + 12];
            const float c0 = alL[e][hd8],     c1 = alL[e + 4][hd8];
            const float c2 = alL[e + 8][hd8], c3 = alL[e + 12][hd8];
            us8 u0 = *(const us8*)(hb + (size_t)s0 * DH);
            us8 u1 = *(const us8*)(hb + (size_t)s1 * DH);
            us8 u2 = *(const us8*)(hb + (size_t)s2 * DH);
            us8 u3 = *(const us8*)(hb + (size_t)s3 * DH);
            #pragma unroll
            for (int i = 0; i < 8; ++i)
                acc8[i] = fmaf(c0, bf2f(u0[i]),
                          fmaf(c1, bf2f(u1[i]),
                          fmaf(c2, bf2f(u2[i]),
                          fmaf(c3, bf2f(u3[i]), acc8[i]))));
        }
        for (; e < cb; e += 4) {
            const int s = srcS[e];
            const float coef = alL[e][hd8];
            us8 u = *(const us8*)(hb + (size_t)s * DH);
            #pragma unroll
            for (int i = 0; i < 8; ++i) acc8[i] = fmaf(coef, bf2f(u[i]), acc8[i]);
        }
        __syncthreads();
    }

    // denominator: reduce per-lane partials over all 64 lanes
    #pragma unroll
    for (int o = 1; o < 64; o <<= 1) {
        #pragma unroll
        for (int k = 0; k < 4; ++k) dsum[k] += __shfl_xor(dsum[k], o, 64);
    }
    // combine the 4 edge-parity groups
    #pragma unroll
    for (int i = 0; i < 8; ++i) {
        acc8[i] += __shfl_xor(acc8[i], 16, 64);
        acc8[i] += __shfl_xor(acc8[i], 32, 64);
    }

    const float inv_d = 1.0f / (dsum[hd8] + pv0[hd8] + 1e-16f);
    const float4 b4a = *(const float4*)(bias + c8 * 8);
    const float4 b4b = *(const float4*)(bias + c8 * 8 + 4);
    float y[8];
    y[0] = acc8[0] * inv_d + b4a.x; y[1] = acc8[1] * inv_d + b4a.y;
    y[2] = acc8[2] * inv_d + b4a.z; y[3] = acc8[3] * inv_d + b4a.w;
    y[4] = acc8[4] * inv_d + b4b.x; y[5] = acc8[5] * inv_d + b4b.y;
    y[6] = acc8[6] * inv_d + b4b.z; y[7] = acc8[7] * inv_d + b4b.w;

    float s1 = 0.f, s2 = 0.f;
    #pragma unroll
    for (int i = 0; i < 8; ++i) { s1 += y[i]; s2 += y[i] * y[i]; }
    #pragma unroll
    for (int o = 1; o < 16; o <<= 1) {
        s1 += __shfl_xor(s1, o, 64);
        s2 += __shfl_xor(s2, o, 64);
    }
    const float mu = s1 * (1.0f / DH);
    const float var = s2 * (1.0f / DH) - mu * mu;
    const float rs = rsqrtf(var + 1e-5f);

    if (sub2 == 0) {
        const float4 g4a = *(const float4*)(gamma + c8 * 8);
        const float4 g4b = *(const float4*)(gamma + c8 * 8 + 4);
        const float4 e4a = *(const float4*)(beta + c8 * 8);
        const float4 e4b = *(const float4*)(beta + c8 * 8 + 4);
        const float4 r4a = *(const float4*)(xres + (size_t)n * DH + c8 * 8);
        const float4 r4b = *(const float4*)(xres + (size_t)n * DH + c8 * 8 + 4);
        const float gv[8] = {g4a.x, g4a.y, g4a.z, g4a.w, g4b.x, g4b.y, g4b.z, g4b.w};
        const float ev[8] = {e4a.x, e4a.y, e4a.z, e4a.w, e4b.x, e4b.y, e4b.z, e4b.w};
        const float rv[8] = {r4a.x, r4a.y, r4a.z, r4a.w, r4b.x, r4b.y, r4b.z, r4b.w};
        float z[8];
        #pragma unroll
        for (int i = 0; i < 8; ++i) {
            float t = (y[i] - mu) * rs * gv[i] + ev[i];
            z[i] = (t > 0.f ? t : __expf(t) - 1.0f) + rv[i];
        }
        *(float4*)(xout + (size_t)n * DH + c8 * 8)     = *(float4*)&z[0];
        *(float4*)(xout + (size_t)n * DH + c8 * 8 + 4) = *(float4*)&z[4];
    }
}

// ---------------- global mean pool ----------------
#define PNODES 64
__global__ __launch_bounds__(128) void pool_kernel(const float* __restrict__ x,
        const int* __restrict__ batch, float* __restrict__ pool, int* __restrict__ gcnt)
{
    int t = threadIdx.x;
    int n0 = blockIdx.x * PNODES;
    if (n0 >= N_NODES) return;
    int n1 = min(n0 + PNODES, N_NODES);
    float acc = 0.f; int cn = 0;
    int curb = batch[n0];
    for (int n = n0; n < n1; ++n) {
        int b = batch[n];
        if (b != curb) {
            atomicAdd(&pool[(size_t)curb * DH + t], acc);
            if (t == 0) atomicAdd(&gcnt[curb], cn);
            acc = 0.f; cn = 0; curb = b;
        }
        acc += x[(size_t)n * DH + t];
        ++cn;
    }
    atomicAdd(&pool[(size_t)curb * DH + t], acc);
    if (t == 0) atomicAdd(&gcnt[curb], cn);
}

__global__ void div_kernel(const float* __restrict__ pool, const int* __restrict__ gcnt,
                           float* __restrict__ out)
{
    int i = blockIdx.x * blockDim.x + threadIdx.x;
    if (i < NB * DH) {
        float c = (float)gcnt[i >> 7];
        out[i] = pool[i] / fmaxf(c, 1.0f);
    }
}

// ---------------- launch ----------------
extern "C" void kernel_launch(void* const* d_in, const int* in_sizes, int n_in,
                              void* d_out, int out_size, void* d_ws, size_t ws_size,
                              hipStream_t stream)
{
    const float* nf    = (const float*)d_in[0];
    const int*   esrc  = (const int*)d_in[1];
    const int*   edst  = esrc + N_EDGES;
    const float* ew    = (const float*)d_in[2];
    const int*   batch = (const int*)d_in[3];
    const float* Wp    = (const float*)d_in[4];
    const float* bp    = (const float*)d_in[5];
    const float* Wl[2]  = {(const float*)d_in[6],  (const float*)d_in[14]};
    const float* asl[2] = {(const float*)d_in[7],  (const float*)d_in[15]};
    const float* adl[2] = {(const float*)d_in[8],  (const float*)d_in[16]};
    const float* Wel[2] = {(const float*)d_in[9],  (const float*)d_in[17]};
    const float* ael[2] = {(const float*)d_in[10], (const float*)d_in[18]};
    const float* bl[2]  = {(const float*)d_in[11], (const float*)d_in[19]};
    const float* gl[2]  = {(const float*)d_in[12], (const float*)d_in[20]};
    const float* bel[2] = {(const float*)d_in[13], (const float*)d_in[21]};
    float* outp = (float*)d_out;

    char* w = (char*)d_ws;
    auto alloc = [&](size_t bytes) { char* p = w; w += (bytes + 255) & ~255ull; return p; };
    float* xA     = (float*)alloc((size_t)N_NODES * DH * 4);
    float* xB     = (float*)alloc((size_t)N_NODES * DH * 4);
    unsigned short* hbuf = (unsigned short*)alloc((size_t)N_NODES * DH * 2);
    float* asrc   = (float*)alloc((size_t)N_NODES * 4 * 4);
    float* adst   = (float*)alloc((size_t)N_NODES * 4 * 4);
    // contiguous zero-init group: pool | gcnt | ews | cnt  (one memset)
    float* pool   = (float*)alloc((size_t)NB * DH * 4);     // 32768 B
    int* gcnt     = (int*)alloc(256);
    float* ews    = (float*)alloc(256);
    int* cnt      = (int*)alloc((size_t)N_NODES * 4);
    int* scanned  = (int*)alloc((size_t)N_NODES * 4);
    int* bsums    = (int*)alloc(1024);
    int* ptr      = (int*)alloc((size_t)(N_NODES + 8) * 4);
    int* cursor   = (int*)alloc((size_t)N_NODES * 4);
    int* srcQ     = (int*)alloc((size_t)N_EDGES * 4);
    float* ewQ    = (float*)alloc((size_t)N_EDGES * 4);

    hipMemsetAsync(pool, 0, (size_t)NB * DH * 4 + 256 + 256 + (size_t)N_NODES * 4, stream);

    const int eb = (N_EDGES + 255) / 256;
    const int sb = (N_NODES + 255) / 256;  // 196

    ewsum_kernel<<<104, 256, 0, stream>>>(ew, ews);
    hist_kernel<<<eb, 256, 0, stream>>>(edst, cnt);
    scan_a<<<sb, 256, 0, stream>>>(cnt, scanned, bsums);
    scan_b<<<1, 256, 0, stream>>>(bsums, sb);
    scan_c<<<sb, 256, 0, stream>>>(scanned, bsums, cnt, ptr, cursor);
    fill_kernel<<<eb, 256, 0, stream>>>(esrc, edst, ew, cursor, srcQ, ewQ);

    const int gb = (N_NODES + 63) / 64;  // 782
    mfma_gemm<DIN, false><<<gb, 256, 0, stream>>>(nf, Wp, bp, xA, N_NODES);

    const float* xin = xA;
    float* xout = xB;
    for (int l = 0; l < 2; ++l) {
        mfma_gemm<DH, true><<<gb, 256, 0, stream>>>(xin, Wl[l], nullptr, hbuf, N_NODES);
        att_kernel<<<(N_NODES + 7) / 8, 256, 0, stream>>>(hbuf, asl[l], adl[l], asrc, adst);
        msg_kernel<<<N_NODES, 64, 0, stream>>>(hbuf, asrc, adst, xin, ptr, srcQ, ewQ, ews,
                                               Wel[l], ael[l], bl[l], gl[l], bel[l], xout);
        float* tmp = (float*)xin; xin = xout; xout = tmp;
    }

    pool_kernel<<<(N_NODES + PNODES - 1) / PNODES, 128, 0, stream>>>(xin, batch, pool, gcnt);
    div_kernel<<<(NB * DH + 255) / 256, 256, 0, stream>>>(pool, gcnt, outp);
}